// Round 2
// baseline (386.231 us; speedup 1.0000x reference)
//
#include <hip/hip_runtime.h>

typedef __bf16 bf16;
typedef __bf16 bf16x4 __attribute__((ext_vector_type(4)));
typedef __bf16 bf16x8 __attribute__((ext_vector_type(8)));
typedef float f32x4 __attribute__((ext_vector_type(4)));

__device__ __forceinline__ f32x4 mfma16(bf16x8 a, bf16x8 b, f32x4 c) {
  return __builtin_amdgcn_mfma_f32_16x16x32_bf16(a, b, c, 0, 0, 0);
}

// ---------------------------------------------------------------------------
// RMSNorm: one wave per 256-elem row. Handles both t and f in one grid.
// ---------------------------------------------------------------------------
__global__ __launch_bounds__(256)
void rms_kernel(const float* __restrict__ t, const float* __restrict__ f,
                const float* __restrict__ w, bf16* __restrict__ tn,
                bf16* __restrict__ fn, int rows_t)
{
  int wave = threadIdx.x >> 6;
  int lane = threadIdx.x & 63;
  int row = blockIdx.x * 4 + wave;
  const float* src;
  bf16* dst;
  if (row < rows_t) {
    src = t + (size_t)row * 256;
    dst = tn + (size_t)row * 256;
  } else {
    int r2 = row - rows_t;
    src = f + (size_t)r2 * 256;
    dst = fn + (size_t)r2 * 256;
  }
  float4 v = reinterpret_cast<const float4*>(src)[lane];
  float ss = v.x * v.x + v.y * v.y + v.z * v.z + v.w * v.w;
  #pragma unroll
  for (int m = 1; m < 64; m <<= 1) ss += __shfl_xor(ss, m);
  float nrm = rsqrtf(ss * (1.0f / 256.0f) + 1e-5f);
  float4 wv = reinterpret_cast<const float4*>(w)[lane];
  bf16x4 o;
  o[0] = (bf16)(v.x * nrm * wv.x);
  o[1] = (bf16)(v.y * nrm * wv.y);
  o[2] = (bf16)(v.z * nrm * wv.z);
  o[3] = (bf16)(v.w * nrm * wv.w);
  *reinterpret_cast<bf16x4*>(dst + lane * 4) = o;
}

// ---------------------------------------------------------------------------
// Weight transpose + fp32->bf16: dst[n*256 + k] = (bf16) src[k*N + n]
// ---------------------------------------------------------------------------
__global__ __launch_bounds__(256)
void transpose_w(const float* __restrict__ src, bf16* __restrict__ dst, int N)
{
  int idx = blockIdx.x * 256 + threadIdx.x;   // idx = n*256 + k
  int k = idx & 255;
  int n = idx >> 8;
  dst[idx] = (bf16)src[(size_t)k * N + n];
}

// ---------------------------------------------------------------------------
// GEMM: out[M=8192, N] = A[8192,256](bf16) @ W[256,N] + bias
// Block tile 64x64, 4 waves in 2x2, each wave 32x32 via 2x2 MFMA frags.
// MODE 0: write Q layout  [b*4+h][t][d]
// MODE 1: write K layout  [b*4+h][f][d]  +  Vt layout [b*4+h][d][f]
// MODE 2: fp32 out = acc + bias + resid(bf16)
// ---------------------------------------------------------------------------
template<int MODE>
__global__ __launch_bounds__(256)
void gemm_k256(const bf16* __restrict__ A, const bf16* __restrict__ Wt,
               const float* __restrict__ bias, bf16* __restrict__ o0,
               bf16* __restrict__ o1, const bf16* __restrict__ resid,
               float* __restrict__ outf, int N)
{
  int wv = threadIdx.x >> 6;
  int lane = threadIdx.x & 63;
  int lr = lane & 15;
  int lk = (lane >> 4) * 8;
  int wm = wv >> 1, wn = wv & 1;
  int nb = N >> 6;
  int bm = blockIdx.x / nb;
  int bn = blockIdx.x - bm * nb;
  int row0 = bm * 64 + wm * 32;
  int col0 = bn * 64 + wn * 32;
  const bf16* Ap = A + (size_t)row0 * 256;
  const bf16* Wp = Wt + (size_t)col0 * 256;

  f32x4 acc[2][2] = {};
  #pragma unroll
  for (int k0 = 0; k0 < 256; k0 += 32) {
    bf16x8 a[2], b[2];
    #pragma unroll
    for (int mi = 0; mi < 2; mi++)
      a[mi] = *reinterpret_cast<const bf16x8*>(Ap + (size_t)(mi * 16 + lr) * 256 + k0 + lk);
    #pragma unroll
    for (int ni = 0; ni < 2; ni++)
      b[ni] = *reinterpret_cast<const bf16x8*>(Wp + (size_t)(ni * 16 + lr) * 256 + k0 + lk);
    #pragma unroll
    for (int mi = 0; mi < 2; mi++)
      #pragma unroll
      for (int ni = 0; ni < 2; ni++)
        acc[mi][ni] = mfma16(a[mi], b[ni], acc[mi][ni]);
  }

  int rb = (lane >> 4) * 4;
  #pragma unroll
  for (int mi = 0; mi < 2; mi++) {
    #pragma unroll
    for (int ni = 0; ni < 2; ni++) {
      int col = col0 + ni * 16 + lr;
      float bv = bias[col];
      #pragma unroll
      for (int r = 0; r < 4; r++) {
        int row = row0 + mi * 16 + rb + r;
        float val = acc[mi][ni][r] + bv;
        if (MODE == 0) {
          int b_ = row >> 12, tt = row & 4095;
          int h = col >> 6, d = col & 63;
          o0[(((size_t)(b_ * 4 + h)) * 4096 + tt) * 64 + d] = (bf16)val;
        } else if (MODE == 1) {
          int b_ = row >> 12, ff = row & 4095;
          if (col < 256) {
            int h = col >> 6, d = col & 63;
            o0[(((size_t)(b_ * 4 + h)) * 4096 + ff) * 64 + d] = (bf16)val;
          } else {
            int c = col - 256;
            int h = c >> 6, d = c & 63;
            o1[(((size_t)(b_ * 4 + h)) * 64 + d) * 4096 + ff] = (bf16)val;
          }
        } else {
          size_t idx = (size_t)row * 256 + col;
          outf[idx] = val + (float)resid[idx];
        }
      }
    }
  }
}

// ---------------------------------------------------------------------------
// Flash attention, f-split version.
// grid = (B*H=8) * (Nt/16=256) blocks; 4 waves/block, wave wv owns the
// f-range [wv*1024, wv*1024+1024). Each wave keeps independent online
// softmax state for the SAME 16 Q rows; partials merged through LDS.
// Q layout [bh][t][d], K layout [bh][f][d], Vt layout [bh][d][f] (bf16).
// ---------------------------------------------------------------------------
__global__ __launch_bounds__(256, 8)
void attn_kernel(const bf16* __restrict__ Q, const bf16* __restrict__ K,
                 const bf16* __restrict__ Vt, bf16* __restrict__ AO)
{
  int bh = blockIdx.x >> 8;        // 0..7  (b*4+h)
  int tb = blockIdx.x & 255;       // 16-row t-tile
  int wv = threadIdx.x >> 6;       // f-split index 0..3
  int lane = threadIdx.x & 63;
  int lr = lane & 15;
  int lg = lane >> 4;
  int lk = lg * 8;
  int t0 = tb * 16;

  const bf16* Qb = Q + ((size_t)bh * 4096 + t0) * 64;
  const bf16* Kb = K + (size_t)bh * 4096 * 64;
  const bf16* Vb = Vt + (size_t)bh * 64 * 4096;

  // Q fragments, with softmax scale (1/8, exact pow2) pre-folded in
  bf16x8 qf[2];
  qf[0] = *reinterpret_cast<const bf16x8*>(Qb + (size_t)lr * 64 + lk);
  qf[1] = *reinterpret_cast<const bf16x8*>(Qb + (size_t)lr * 64 + 32 + lk);
  #pragma unroll
  for (int i = 0; i < 8; i++) {
    qf[0][i] = (bf16)((float)qf[0][i] * 0.125f);
    qf[1][i] = (bf16)((float)qf[1][i] * 0.125f);
  }

  __shared__ union {
    bf16 p[4][16][72];                       // per-wave P tile (loop phase)
    struct {
      float o[4][16][68];                    // per-wave unnormalized O
      float ml[4][2][16];                    // per-wave m, l per row
    } c;                                     // combine phase
  } lds;
  bf16* myp = &lds.p[wv][0][0];

  f32x4 o[4] = {};
  float mrow[4] = {-3.0e38f, -3.0e38f, -3.0e38f, -3.0e38f};
  float lrow[4] = {0.f, 0.f, 0.f, 0.f};

  int fbeg = wv * 1024;
  for (int f0 = fbeg; f0 < fbeg + 1024; f0 += 64) {
    // S = Q K^T for this 16x64 tile (Q pre-scaled)
    f32x4 s[4] = {};
    #pragma unroll
    for (int fi = 0; fi < 4; fi++) {
      const bf16* kp = Kb + (size_t)(f0 + fi * 16 + lr) * 64 + lk;
      bf16x8 k0 = *reinterpret_cast<const bf16x8*>(kp);
      bf16x8 k1 = *reinterpret_cast<const bf16x8*>(kp + 32);
      s[fi] = mfma16(qf[0], k0, s[fi]);
      s[fi] = mfma16(qf[1], k1, s[fi]);
    }
    // online softmax; rows live in 16-lane groups (xor 1,2,4,8)
    float alpha[4];
    #pragma unroll
    for (int r = 0; r < 4; r++) {
      float tm = fmaxf(fmaxf(s[0][r], s[1][r]), fmaxf(s[2][r], s[3][r]));
      #pragma unroll
      for (int m = 1; m < 16; m <<= 1) tm = fmaxf(tm, __shfl_xor(tm, m));
      float mn = fmaxf(mrow[r], tm);
      alpha[r] = __expf(mrow[r] - mn);
      mrow[r] = mn;
      float ps = 0.f;
      #pragma unroll
      for (int fi = 0; fi < 4; fi++) {
        float p = __expf(s[fi][r] - mn);
        s[fi][r] = p;
        ps += p;
      }
      #pragma unroll
      for (int m = 1; m < 16; m <<= 1) ps += __shfl_xor(ps, m);
      lrow[r] = lrow[r] * alpha[r] + ps;
    }
    #pragma unroll
    for (int df = 0; df < 4; df++)
      #pragma unroll
      for (int r = 0; r < 4; r++) o[df][r] *= alpha[r];

    // P -> LDS (bf16), re-read as A-fragments
    #pragma unroll
    for (int fi = 0; fi < 4; fi++)
      #pragma unroll
      for (int r = 0; r < 4; r++)
        myp[(lg * 4 + r) * 72 + fi * 16 + lr] = (bf16)s[fi][r];

    bf16x8 pa0 = *reinterpret_cast<const bf16x8*>(myp + lr * 72 + lk);
    bf16x8 pa1 = *reinterpret_cast<const bf16x8*>(myp + lr * 72 + 32 + lk);

    #pragma unroll
    for (int df = 0; df < 4; df++) {
      const bf16* vp = Vb + (size_t)(df * 16 + lr) * 4096 + f0 + lk;
      bf16x8 v0 = *reinterpret_cast<const bf16x8*>(vp);
      bf16x8 v1 = *reinterpret_cast<const bf16x8*>(vp + 32);
      o[df] = mfma16(pa0, v0, o[df]);
      o[df] = mfma16(pa1, v1, o[df]);
    }
  }

  // ---- merge the 4 f-split partials through LDS ----
  __syncthreads();   // everyone done with the p-region before c overwrites it
  #pragma unroll
  for (int df = 0; df < 4; df++)
    #pragma unroll
    for (int r = 0; r < 4; r++)
      lds.c.o[wv][lg * 4 + r][df * 16 + lr] = o[df][r];
  if (lr == 0) {
    #pragma unroll
    for (int r = 0; r < 4; r++) {
      lds.c.ml[wv][0][lg * 4 + r] = mrow[r];
      lds.c.ml[wv][1][lg * 4 + r] = lrow[r];
    }
  }
  __syncthreads();

  // wave wv merges column slice d = wv*16 + lr, rows lg*4 + r
  int b_ = bh >> 2, h = bh & 3;
  #pragma unroll
  for (int r = 0; r < 4; r++) {
    int row = lg * 4 + r;
    float M = -3.0e38f;
    #pragma unroll
    for (int s = 0; s < 4; s++) M = fmaxf(M, lds.c.ml[s][0][row]);
    float L = 0.f, O = 0.f;
    #pragma unroll
    for (int s = 0; s < 4; s++) {
      float fs = __expf(lds.c.ml[s][0][row] - M);
      L += lds.c.ml[s][1][row] * fs;
      O += lds.c.o[s][row][wv * 16 + lr] * fs;
    }
    AO[((size_t)b_ * 4096 + t0 + row) * 256 + h * 64 + wv * 16 + lr] = (bf16)(O / L);
  }
}

// ---------------------------------------------------------------------------
extern "C" void kernel_launch(void* const* d_in, const int* in_sizes, int n_in,
                              void* d_out, int out_size, void* d_ws, size_t ws_size,
                              hipStream_t stream) {
  const float* t   = (const float*)d_in[0];
  const float* f   = (const float*)d_in[1];
  const float* nw  = (const float*)d_in[2];
  const float* wq  = (const float*)d_in[3];
  const float* bq  = (const float*)d_in[4];
  const float* wkv = (const float*)d_in[5];
  const float* bkv = (const float*)d_in[6];
  const float* wp  = (const float*)d_in[7];
  const float* bp  = (const float*)d_in[8];
  float* out = (float*)d_out;

  bf16* ws = (bf16*)d_ws;
  const size_t NTOK = 2097152;        // 2*4096*256
  bf16* tn   = ws;
  bf16* fn   = ws + NTOK;
  bf16* q    = ws + 2 * NTOK;
  bf16* k    = ws + 3 * NTOK;
  bf16* vt   = ws + 4 * NTOK;
  bf16* ao   = ws + 5 * NTOK;
  bf16* wqT  = ws + 6 * NTOK;
  bf16* wkvT = wqT + 65536;
  bf16* wpT  = wkvT + 131072;

  transpose_w<<<256, 256, 0, stream>>>(wq, wqT, 256);
  transpose_w<<<512, 256, 0, stream>>>(wkv, wkvT, 512);
  transpose_w<<<256, 256, 0, stream>>>(wp, wpT, 256);
  rms_kernel<<<4096, 256, 0, stream>>>(t, f, nw, tn, fn, 8192);
  gemm_k256<0><<<512, 256, 0, stream>>>(tn, wqT, bq, q, nullptr, nullptr, nullptr, 256);
  gemm_k256<1><<<1024, 256, 0, stream>>>(fn, wkvT, bkv, k, vt, nullptr, nullptr, 512);
  attn_kernel<<<2048, 256, 0, stream>>>(q, k, vt, ao);
  gemm_k256<2><<<512, 256, 0, stream>>>(ao, wpT, bp, nullptr, nullptr, tn, out, 256);
}

// Round 3
// 293.556 us; speedup vs baseline: 1.3157x; 1.3157x over previous
//
#include <hip/hip_runtime.h>

typedef __bf16 bf16;
typedef __bf16 bf16x4 __attribute__((ext_vector_type(4)));
typedef __bf16 bf16x8 __attribute__((ext_vector_type(8)));
typedef float f32x4 __attribute__((ext_vector_type(4)));

__device__ __forceinline__ f32x4 mfma16(bf16x8 a, bf16x8 b, f32x4 c) {
  return __builtin_amdgcn_mfma_f32_16x16x32_bf16(a, b, c, 0, 0, 0);
}

// ---------------------------------------------------------------------------
// RMSNorm: one wave per 256-elem row. Handles both t and f in one grid.
// ---------------------------------------------------------------------------
__global__ __launch_bounds__(256)
void rms_kernel(const float* __restrict__ t, const float* __restrict__ f,
                const float* __restrict__ w, bf16* __restrict__ tn,
                bf16* __restrict__ fn, int rows_t)
{
  int wave = threadIdx.x >> 6;
  int lane = threadIdx.x & 63;
  int row = blockIdx.x * 4 + wave;
  const float* src;
  bf16* dst;
  if (row < rows_t) {
    src = t + (size_t)row * 256;
    dst = tn + (size_t)row * 256;
  } else {
    int r2 = row - rows_t;
    src = f + (size_t)r2 * 256;
    dst = fn + (size_t)r2 * 256;
  }
  float4 v = reinterpret_cast<const float4*>(src)[lane];
  float ss = v.x * v.x + v.y * v.y + v.z * v.z + v.w * v.w;
  #pragma unroll
  for (int m = 1; m < 64; m <<= 1) ss += __shfl_xor(ss, m);
  float nrm = rsqrtf(ss * (1.0f / 256.0f) + 1e-5f);
  float4 wv = reinterpret_cast<const float4*>(w)[lane];
  bf16x4 o;
  o[0] = (bf16)(v.x * nrm * wv.x);
  o[1] = (bf16)(v.y * nrm * wv.y);
  o[2] = (bf16)(v.z * nrm * wv.z);
  o[3] = (bf16)(v.w * nrm * wv.w);
  *reinterpret_cast<bf16x4*>(dst + lane * 4) = o;
}

// ---------------------------------------------------------------------------
// Weight transpose + fp32->bf16: dst[n*256 + k] = (bf16) src[k*N + n]
// ---------------------------------------------------------------------------
__global__ __launch_bounds__(256)
void transpose_w(const float* __restrict__ src, bf16* __restrict__ dst, int N)
{
  int idx = blockIdx.x * 256 + threadIdx.x;   // idx = n*256 + k
  int k = idx & 255;
  int n = idx >> 8;
  dst[idx] = (bf16)src[(size_t)k * N + n];
}

// ---------------------------------------------------------------------------
// GEMM: out[M=8192, N] = A[8192,256](bf16) @ W[256,N] + bias
// Block tile 64x64, 4 waves in 2x2, each wave 32x32 via 2x2 MFMA frags.
// MODE 0: write Q layout  [b*4+h][t][d]
// MODE 1: write K layout  [b*4+h][f][d]  +  Vt layout [b*4+h][d][f]
// MODE 2: fp32 out = acc + bias + resid(bf16)
// ---------------------------------------------------------------------------
template<int MODE>
__global__ __launch_bounds__(256)
void gemm_k256(const bf16* __restrict__ A, const bf16* __restrict__ Wt,
               const float* __restrict__ bias, bf16* __restrict__ o0,
               bf16* __restrict__ o1, const bf16* __restrict__ resid,
               float* __restrict__ outf, int N)
{
  int wv = threadIdx.x >> 6;
  int lane = threadIdx.x & 63;
  int lr = lane & 15;
  int lk = (lane >> 4) * 8;
  int wm = wv >> 1, wn = wv & 1;
  int nb = N >> 6;
  int bm = blockIdx.x / nb;
  int bn = blockIdx.x - bm * nb;
  int row0 = bm * 64 + wm * 32;
  int col0 = bn * 64 + wn * 32;
  const bf16* Ap = A + (size_t)row0 * 256;
  const bf16* Wp = Wt + (size_t)col0 * 256;

  f32x4 acc[2][2] = {};
  #pragma unroll
  for (int k0 = 0; k0 < 256; k0 += 32) {
    bf16x8 a[2], b[2];
    #pragma unroll
    for (int mi = 0; mi < 2; mi++)
      a[mi] = *reinterpret_cast<const bf16x8*>(Ap + (size_t)(mi * 16 + lr) * 256 + k0 + lk);
    #pragma unroll
    for (int ni = 0; ni < 2; ni++)
      b[ni] = *reinterpret_cast<const bf16x8*>(Wp + (size_t)(ni * 16 + lr) * 256 + k0 + lk);
    #pragma unroll
    for (int mi = 0; mi < 2; mi++)
      #pragma unroll
      for (int ni = 0; ni < 2; ni++)
        acc[mi][ni] = mfma16(a[mi], b[ni], acc[mi][ni]);
  }

  int rb = (lane >> 4) * 4;
  #pragma unroll
  for (int mi = 0; mi < 2; mi++) {
    #pragma unroll
    for (int ni = 0; ni < 2; ni++) {
      int col = col0 + ni * 16 + lr;
      float bv = bias[col];
      #pragma unroll
      for (int r = 0; r < 4; r++) {
        int row = row0 + mi * 16 + rb + r;
        float val = acc[mi][ni][r] + bv;
        if (MODE == 0) {
          int b_ = row >> 12, tt = row & 4095;
          int h = col >> 6, d = col & 63;
          o0[(((size_t)(b_ * 4 + h)) * 4096 + tt) * 64 + d] = (bf16)val;
        } else if (MODE == 1) {
          int b_ = row >> 12, ff = row & 4095;
          if (col < 256) {
            int h = col >> 6, d = col & 63;
            o0[(((size_t)(b_ * 4 + h)) * 4096 + ff) * 64 + d] = (bf16)val;
          } else {
            int c = col - 256;
            int h = c >> 6, d = c & 63;
            o1[(((size_t)(b_ * 4 + h)) * 64 + d) * 4096 + ff] = (bf16)val;
          }
        } else {
          size_t idx = (size_t)row * 256 + col;
          outf[idx] = val + (float)resid[idx];
        }
      }
    }
  }
}

// ---------------------------------------------------------------------------
// Flash attention, f-split version.
// grid = (B*H=8) * (Nt/16=256) blocks; 4 waves/block, wave wv owns the
// f-range [wv*1024, wv*1024+1024). Each wave keeps independent online
// softmax state for the SAME 16 Q rows; partials merged through LDS.
// Q layout [bh][t][d], K layout [bh][f][d], Vt layout [bh][d][f] (bf16).
// launch_bounds(256,4): 128-VGPR budget. (256,8) forced a 64-reg fit and
// spilled accumulators to scratch -> 700 MB HBM traffic (round-2 lesson).
// ---------------------------------------------------------------------------
__global__ __launch_bounds__(256, 4)
void attn_kernel(const bf16* __restrict__ Q, const bf16* __restrict__ K,
                 const bf16* __restrict__ Vt, bf16* __restrict__ AO)
{
  int bh = blockIdx.x >> 8;        // 0..7  (b*4+h)
  int tb = blockIdx.x & 255;       // 16-row t-tile
  int wv = threadIdx.x >> 6;       // f-split index 0..3
  int lane = threadIdx.x & 63;
  int lr = lane & 15;
  int lg = lane >> 4;
  int lk = lg * 8;
  int t0 = tb * 16;

  const bf16* Qb = Q + ((size_t)bh * 4096 + t0) * 64;
  const bf16* Kb = K + (size_t)bh * 4096 * 64;
  const bf16* Vb = Vt + (size_t)bh * 64 * 4096;

  // Q fragments, with softmax scale (1/8, exact pow2) pre-folded in
  bf16x8 qf[2];
  qf[0] = *reinterpret_cast<const bf16x8*>(Qb + (size_t)lr * 64 + lk);
  qf[1] = *reinterpret_cast<const bf16x8*>(Qb + (size_t)lr * 64 + 32 + lk);
  #pragma unroll
  for (int i = 0; i < 8; i++) {
    qf[0][i] = (bf16)((float)qf[0][i] * 0.125f);
    qf[1][i] = (bf16)((float)qf[1][i] * 0.125f);
  }

  __shared__ union {
    bf16 p[4][16][72];                       // per-wave P tile (loop phase)
    struct {
      float o[4][16][68];                    // per-wave unnormalized O
      float ml[4][2][16];                    // per-wave m, l per row
    } c;                                     // combine phase
  } lds;
  bf16* myp = &lds.p[wv][0][0];

  f32x4 o[4] = {};
  float mrow[4] = {-3.0e38f, -3.0e38f, -3.0e38f, -3.0e38f};
  float lrow[4] = {0.f, 0.f, 0.f, 0.f};

  int fbeg = wv * 1024;
  for (int f0 = fbeg; f0 < fbeg + 1024; f0 += 64) {
    // S = Q K^T for this 16x64 tile (Q pre-scaled)
    f32x4 s[4] = {};
    #pragma unroll
    for (int fi = 0; fi < 4; fi++) {
      const bf16* kp = Kb + (size_t)(f0 + fi * 16 + lr) * 64 + lk;
      bf16x8 k0 = *reinterpret_cast<const bf16x8*>(kp);
      bf16x8 k1 = *reinterpret_cast<const bf16x8*>(kp + 32);
      s[fi] = mfma16(qf[0], k0, s[fi]);
      s[fi] = mfma16(qf[1], k1, s[fi]);
    }
    // online softmax; rows live in 16-lane groups (xor 1,2,4,8)
    float alpha[4];
    #pragma unroll
    for (int r = 0; r < 4; r++) {
      float tm = fmaxf(fmaxf(s[0][r], s[1][r]), fmaxf(s[2][r], s[3][r]));
      #pragma unroll
      for (int m = 1; m < 16; m <<= 1) tm = fmaxf(tm, __shfl_xor(tm, m));
      float mn = fmaxf(mrow[r], tm);
      alpha[r] = __expf(mrow[r] - mn);
      mrow[r] = mn;
      float ps = 0.f;
      #pragma unroll
      for (int fi = 0; fi < 4; fi++) {
        float p = __expf(s[fi][r] - mn);
        s[fi][r] = p;
        ps += p;
      }
      #pragma unroll
      for (int m = 1; m < 16; m <<= 1) ps += __shfl_xor(ps, m);
      lrow[r] = lrow[r] * alpha[r] + ps;
    }
    #pragma unroll
    for (int df = 0; df < 4; df++)
      #pragma unroll
      for (int r = 0; r < 4; r++) o[df][r] *= alpha[r];

    // P -> LDS (bf16), re-read as A-fragments
    #pragma unroll
    for (int fi = 0; fi < 4; fi++)
      #pragma unroll
      for (int r = 0; r < 4; r++)
        myp[(lg * 4 + r) * 72 + fi * 16 + lr] = (bf16)s[fi][r];

    bf16x8 pa0 = *reinterpret_cast<const bf16x8*>(myp + lr * 72 + lk);
    bf16x8 pa1 = *reinterpret_cast<const bf16x8*>(myp + lr * 72 + 32 + lk);

    #pragma unroll
    for (int df = 0; df < 4; df++) {
      const bf16* vp = Vb + (size_t)(df * 16 + lr) * 4096 + f0 + lk;
      bf16x8 v0 = *reinterpret_cast<const bf16x8*>(vp);
      bf16x8 v1 = *reinterpret_cast<const bf16x8*>(vp + 32);
      o[df] = mfma16(pa0, v0, o[df]);
      o[df] = mfma16(pa1, v1, o[df]);
    }
  }

  // ---- merge the 4 f-split partials through LDS ----
  __syncthreads();   // everyone done with the p-region before c overwrites it
  #pragma unroll
  for (int df = 0; df < 4; df++)
    #pragma unroll
    for (int r = 0; r < 4; r++)
      lds.c.o[wv][lg * 4 + r][df * 16 + lr] = o[df][r];
  if (lr == 0) {
    #pragma unroll
    for (int r = 0; r < 4; r++) {
      lds.c.ml[wv][0][lg * 4 + r] = mrow[r];
      lds.c.ml[wv][1][lg * 4 + r] = lrow[r];
    }
  }
  __syncthreads();

  // wave wv merges column slice d = wv*16 + lr, rows lg*4 + r
  int b_ = bh >> 2, h = bh & 3;
  #pragma unroll
  for (int r = 0; r < 4; r++) {
    int row = lg * 4 + r;
    float M = -3.0e38f;
    #pragma unroll
    for (int s = 0; s < 4; s++) M = fmaxf(M, lds.c.ml[s][0][row]);
    float L = 0.f, O = 0.f;
    #pragma unroll
    for (int s = 0; s < 4; s++) {
      float fs = __expf(lds.c.ml[s][0][row] - M);
      L += lds.c.ml[s][1][row] * fs;
      O += lds.c.o[s][row][wv * 16 + lr] * fs;
    }
    AO[((size_t)b_ * 4096 + t0 + row) * 256 + h * 64 + wv * 16 + lr] = (bf16)(O / L);
  }
}

// ---------------------------------------------------------------------------
extern "C" void kernel_launch(void* const* d_in, const int* in_sizes, int n_in,
                              void* d_out, int out_size, void* d_ws, size_t ws_size,
                              hipStream_t stream) {
  const float* t   = (const float*)d_in[0];
  const float* f   = (const float*)d_in[1];
  const float* nw  = (const float*)d_in[2];
  const float* wq  = (const float*)d_in[3];
  const float* bq  = (const float*)d_in[4];
  const float* wkv = (const float*)d_in[5];
  const float* bkv = (const float*)d_in[6];
  const float* wp  = (const float*)d_in[7];
  const float* bp  = (const float*)d_in[8];
  float* out = (float*)d_out;

  bf16* ws = (bf16*)d_ws;
  const size_t NTOK = 2097152;        // 2*4096*256
  bf16* tn   = ws;
  bf16* fn   = ws + NTOK;
  bf16* q    = ws + 2 * NTOK;
  bf16* k    = ws + 3 * NTOK;
  bf16* vt   = ws + 4 * NTOK;
  bf16* ao   = ws + 5 * NTOK;
  bf16* wqT  = ws + 6 * NTOK;
  bf16* wkvT = wqT + 65536;
  bf16* wpT  = wkvT + 131072;

  transpose_w<<<256, 256, 0, stream>>>(wq, wqT, 256);
  transpose_w<<<512, 256, 0, stream>>>(wkv, wkvT, 512);
  transpose_w<<<256, 256, 0, stream>>>(wp, wpT, 256);
  rms_kernel<<<4096, 256, 0, stream>>>(t, f, nw, tn, fn, 8192);
  gemm_k256<0><<<512, 256, 0, stream>>>(tn, wqT, bq, q, nullptr, nullptr, nullptr, 256);
  gemm_k256<1><<<1024, 256, 0, stream>>>(fn, wkvT, bkv, k, vt, nullptr, nullptr, 512);
  attn_kernel<<<2048, 256, 0, stream>>>(q, k, vt, ao);
  gemm_k256<2><<<512, 256, 0, stream>>>(ao, wpT, bp, nullptr, nullptr, tn, out, 256);
}

// Round 4
// 185.886 us; speedup vs baseline: 2.0778x; 1.5792x over previous
//
#include <hip/hip_runtime.h>

typedef __bf16 bf16;
typedef __bf16 bf16x4 __attribute__((ext_vector_type(4)));
typedef __bf16 bf16x8 __attribute__((ext_vector_type(8)));
typedef float f32x4 __attribute__((ext_vector_type(4)));
typedef float f32x16 __attribute__((ext_vector_type(16)));

__device__ __forceinline__ f32x4 mfma16(bf16x8 a, bf16x8 b, f32x4 c) {
  return __builtin_amdgcn_mfma_f32_16x16x32_bf16(a, b, c, 0, 0, 0);
}
__device__ __forceinline__ f32x16 mfma32(bf16x8 a, bf16x8 b, f32x16 c) {
  return __builtin_amdgcn_mfma_f32_32x32x16_bf16(a, b, c, 0, 0, 0);
}

__device__ __forceinline__ unsigned pack2(float lo, float hi) {
  unsigned short a = __builtin_bit_cast(unsigned short, (bf16)lo);
  unsigned short b = __builtin_bit_cast(unsigned short, (bf16)hi);
  return ((unsigned)b << 16) | (unsigned)a;
}

// ---------------------------------------------------------------------------
// RMSNorm: one wave per 256-elem row. Handles both t and f in one grid.
// ---------------------------------------------------------------------------
__global__ __launch_bounds__(256)
void rms_kernel(const float* __restrict__ t, const float* __restrict__ f,
                const float* __restrict__ w, bf16* __restrict__ tn,
                bf16* __restrict__ fn, int rows_t)
{
  int wave = threadIdx.x >> 6;
  int lane = threadIdx.x & 63;
  int row = blockIdx.x * 4 + wave;
  const float* src;
  bf16* dst;
  if (row < rows_t) {
    src = t + (size_t)row * 256;
    dst = tn + (size_t)row * 256;
  } else {
    int r2 = row - rows_t;
    src = f + (size_t)r2 * 256;
    dst = fn + (size_t)r2 * 256;
  }
  float4 v = reinterpret_cast<const float4*>(src)[lane];
  float ss = v.x * v.x + v.y * v.y + v.z * v.z + v.w * v.w;
  #pragma unroll
  for (int m = 1; m < 64; m <<= 1) ss += __shfl_xor(ss, m);
  float nrm = rsqrtf(ss * (1.0f / 256.0f) + 1e-5f);
  float4 wv = reinterpret_cast<const float4*>(w)[lane];
  bf16x4 o;
  o[0] = (bf16)(v.x * nrm * wv.x);
  o[1] = (bf16)(v.y * nrm * wv.y);
  o[2] = (bf16)(v.z * nrm * wv.z);
  o[3] = (bf16)(v.w * nrm * wv.w);
  *reinterpret_cast<bf16x4*>(dst + lane * 4) = o;
}

// ---------------------------------------------------------------------------
// Weight transpose + fp32->bf16: dst[n*256 + k] = (bf16) src[k*N + n]
// ---------------------------------------------------------------------------
__global__ __launch_bounds__(256)
void transpose_w(const float* __restrict__ src, bf16* __restrict__ dst, int N)
{
  int idx = blockIdx.x * 256 + threadIdx.x;   // idx = n*256 + k
  int k = idx & 255;
  int n = idx >> 8;
  dst[idx] = (bf16)src[(size_t)k * N + n];
}

// ---------------------------------------------------------------------------
// GEMM: out[M=8192, N] = A[8192,256](bf16) @ W[256,N] + bias
// Block tile 64x64, 4 waves in 2x2, each wave 32x32 via 2x2 MFMA frags.
// MODE 0: write Q layout  [b*4+h][t][d]
// MODE 1: write K layout  [b*4+h][f][d]  +  Vt layout [b*4+h][d][f]
// MODE 2: fp32 out = acc + bias + resid(bf16)
// ---------------------------------------------------------------------------
template<int MODE>
__global__ __launch_bounds__(256)
void gemm_k256(const bf16* __restrict__ A, const bf16* __restrict__ Wt,
               const float* __restrict__ bias, bf16* __restrict__ o0,
               bf16* __restrict__ o1, const bf16* __restrict__ resid,
               float* __restrict__ outf, int N)
{
  int wv = threadIdx.x >> 6;
  int lane = threadIdx.x & 63;
  int lr = lane & 15;
  int lk = (lane >> 4) * 8;
  int wm = wv >> 1, wn = wv & 1;
  int nb = N >> 6;
  int bm = blockIdx.x / nb;
  int bn = blockIdx.x - bm * nb;
  int row0 = bm * 64 + wm * 32;
  int col0 = bn * 64 + wn * 32;
  const bf16* Ap = A + (size_t)row0 * 256;
  const bf16* Wp = Wt + (size_t)col0 * 256;

  f32x4 acc[2][2] = {};
  #pragma unroll
  for (int k0 = 0; k0 < 256; k0 += 32) {
    bf16x8 a[2], b[2];
    #pragma unroll
    for (int mi = 0; mi < 2; mi++)
      a[mi] = *reinterpret_cast<const bf16x8*>(Ap + (size_t)(mi * 16 + lr) * 256 + k0 + lk);
    #pragma unroll
    for (int ni = 0; ni < 2; ni++)
      b[ni] = *reinterpret_cast<const bf16x8*>(Wp + (size_t)(ni * 16 + lr) * 256 + k0 + lk);
    #pragma unroll
    for (int mi = 0; mi < 2; mi++)
      #pragma unroll
      for (int ni = 0; ni < 2; ni++)
        acc[mi][ni] = mfma16(a[mi], b[ni], acc[mi][ni]);
  }

  int rb = (lane >> 4) * 4;
  #pragma unroll
  for (int mi = 0; mi < 2; mi++) {
    #pragma unroll
    for (int ni = 0; ni < 2; ni++) {
      int col = col0 + ni * 16 + lr;
      float bv = bias[col];
      #pragma unroll
      for (int r = 0; r < 4; r++) {
        int row = row0 + mi * 16 + rb + r;
        float val = acc[mi][ni][r] + bv;
        if (MODE == 0) {
          int b_ = row >> 12, tt = row & 4095;
          int h = col >> 6, d = col & 63;
          o0[(((size_t)(b_ * 4 + h)) * 4096 + tt) * 64 + d] = (bf16)val;
        } else if (MODE == 1) {
          int b_ = row >> 12, ff = row & 4095;
          if (col < 256) {
            int h = col >> 6, d = col & 63;
            o0[(((size_t)(b_ * 4 + h)) * 4096 + ff) * 64 + d] = (bf16)val;
          } else {
            int c = col - 256;
            int h = c >> 6, d = c & 63;
            o1[(((size_t)(b_ * 4 + h)) * 64 + d) * 4096 + ff] = (bf16)val;
          }
        } else {
          size_t idx = (size_t)row * 256 + col;
          outf[idx] = val + (float)resid[idx];
        }
      }
    }
  }
}

// ---------------------------------------------------------------------------
// Flash attention v2: swapped-operand 32x32 MFMA, in-register softmax.
// grid = (B*H=8) * (Nt/32=128) blocks; 4 waves/block, wave wv owns the
// f-range [wv*1024, wv*1024+1024) over the SAME 32 q rows; merge via LDS.
//
// S^T = mfma32(A=K(32f x 16k), B=Q(16k x 32q)): lane holds 16 S-values of
// column q=lane&31, rows f = (r&3)+8*(r>>2)+4*(lane>>5). Softmax per lane:
// 15 in-lane fmax + 1 shfl_xor(32); m,l are per-lane scalars.
// P^T -> PV B-fragment (k=f): lane-half h needs k=8h+i, i.e. half its own
// packed words + the complementary words of the partner half -> 4
// shfl_xor(·,32) exchanges per tile. O^T accumulated via
// mfma32(A=Vt(32d x 16f), B=P^T), Dh=64 -> 2 f32x16 accumulators.
// ---------------------------------------------------------------------------
__global__ __launch_bounds__(256)
void attn_kernel(const bf16* __restrict__ Q, const bf16* __restrict__ K,
                 const bf16* __restrict__ Vt, bf16* __restrict__ AO)
{
  int bh = blockIdx.x >> 7;        // 0..7  (b*4+h)
  int tb = blockIdx.x & 127;       // 32-row q tile
  int wv = threadIdx.x >> 6;       // f-split index 0..3
  int lane = threadIdx.x & 63;
  int lq = lane & 31;              // q column (also f-row / d-row for A frags)
  int h32 = lane >> 5;             // lane half
  int t0 = tb * 32;

  const bf16* Qb = Q + ((size_t)bh * 4096 + t0) * 64;
  const bf16* Kb = K + (size_t)bh * 4096 * 64;
  const bf16* Vb = Vt + (size_t)bh * 64 * 4096;

  // Q as B-fragments: B[k][q], k = kc*16 + h32*8 + i. Prescale by 1/8.
  bf16x8 qf[4];
  #pragma unroll
  for (int kc = 0; kc < 4; kc++) {
    qf[kc] = *reinterpret_cast<const bf16x8*>(Qb + (size_t)lq * 64 + kc * 16 + h32 * 8);
    #pragma unroll
    for (int i = 0; i < 8; i++) qf[kc][i] = (bf16)((float)qf[kc][i] * 0.125f);
  }

  f32x16 oa[2] = {};               // O^T accumulators (d-blocks 0,1)
  float m = -3.0e38f, l = 0.f;

  int fbeg = wv * 1024;
  for (int f0 = fbeg; f0 < fbeg + 1024; f0 += 32) {
    // S^T (32f x 32q) = K . Q^T
    f32x16 st = {};
    #pragma unroll
    for (int kc = 0; kc < 4; kc++) {
      bf16x8 kf = *reinterpret_cast<const bf16x8*>(
          Kb + (size_t)(f0 + lq) * 64 + kc * 16 + h32 * 8);
      st = mfma32(kf, qf[kc], st);
    }

    // online softmax: all 32 f-values of column q live in (lane, lane^32)
    float tm = st[0];
    #pragma unroll
    for (int r = 1; r < 16; r++) tm = fmaxf(tm, st[r]);
    tm = fmaxf(tm, __shfl_xor(tm, 32));
    float mn = fmaxf(m, tm);
    float alpha = __expf(m - mn);
    m = mn;
    float p[16], ps = 0.f;
    #pragma unroll
    for (int r = 0; r < 16; r++) { p[r] = __expf(st[r] - mn); ps += p[r]; }
    ps += __shfl_xor(ps, 32);
    l = l * alpha + ps;
    #pragma unroll
    for (int r = 0; r < 16; r++) { oa[0][r] *= alpha; oa[1][r] *= alpha; }

    // P^T -> B-fragments. w[j] = pack(p[2j], p[2j+1]).
    unsigned w[8];
    #pragma unroll
    for (int j = 0; j < 8; j++) w[j] = pack2(p[2 * j], p[2 * j + 1]);
    // cross-half exchanges: send what the partner needs
    unsigned e0 = (unsigned)__shfl_xor((int)(h32 ? w[0] : w[2]), 32);
    unsigned e1 = (unsigned)__shfl_xor((int)(h32 ? w[1] : w[3]), 32);
    unsigned e2 = (unsigned)__shfl_xor((int)(h32 ? w[4] : w[6]), 32);
    unsigned e3 = (unsigned)__shfl_xor((int)(h32 ? w[5] : w[7]), 32);
    union { unsigned u[4]; bf16x8 v; } ub0, ub1;
    ub0.u[0] = h32 ? e0 : w[0];
    ub0.u[1] = h32 ? e1 : w[1];
    ub0.u[2] = h32 ? w[2] : e0;
    ub0.u[3] = h32 ? w[3] : e1;
    ub1.u[0] = h32 ? e2 : w[4];
    ub1.u[1] = h32 ? e3 : w[5];
    ub1.u[2] = h32 ? w[6] : e2;
    ub1.u[3] = h32 ? w[7] : e3;

    // O^T += Vt . P^T
    #pragma unroll
    for (int db = 0; db < 2; db++) {
      const bf16* vp = Vb + (size_t)(db * 32 + lq) * 4096 + f0 + h32 * 8;
      bf16x8 v0 = *reinterpret_cast<const bf16x8*>(vp);
      bf16x8 v1 = *reinterpret_cast<const bf16x8*>(vp + 16);
      oa[db] = mfma32(v0, ub0.v, oa[db]);
      oa[db] = mfma32(v1, ub1.v, oa[db]);
    }
  }

  // ---- merge the 4 f-split partials through LDS ----
  __shared__ float ols[4][64][33];
  __shared__ float mls[4][2][32];
  #pragma unroll
  for (int db = 0; db < 2; db++)
    #pragma unroll
    for (int r = 0; r < 16; r++) {
      int d = db * 32 + (r & 3) + 8 * (r >> 2) + 4 * h32;
      ols[wv][d][lq] = oa[db][r];
    }
  if (lane < 32) {
    mls[wv][0][lq] = m;
    mls[wv][1][lq] = l;
  }
  __syncthreads();

  int b_ = bh >> 2, hh = bh & 3;
  #pragma unroll
  for (int j = 0; j < 8; j++) {
    int e = threadIdx.x + j * 256;     // 2048 = 32q x 64d
    int q = e >> 6, d = e & 63;
    float M = fmaxf(fmaxf(mls[0][0][q], mls[1][0][q]),
                    fmaxf(mls[2][0][q], mls[3][0][q]));
    float L = 0.f, O = 0.f;
    #pragma unroll
    for (int s = 0; s < 4; s++) {
      float fs = __expf(mls[s][0][q] - M);
      L += mls[s][1][q] * fs;
      O += ols[s][d][q] * fs;
    }
    AO[((size_t)b_ * 4096 + t0 + q) * 256 + hh * 64 + d] = (bf16)(O / L);
  }
}

// ---------------------------------------------------------------------------
extern "C" void kernel_launch(void* const* d_in, const int* in_sizes, int n_in,
                              void* d_out, int out_size, void* d_ws, size_t ws_size,
                              hipStream_t stream) {
  const float* t   = (const float*)d_in[0];
  const float* f   = (const float*)d_in[1];
  const float* nw  = (const float*)d_in[2];
  const float* wq  = (const float*)d_in[3];
  const float* bq  = (const float*)d_in[4];
  const float* wkv = (const float*)d_in[5];
  const float* bkv = (const float*)d_in[6];
  const float* wp  = (const float*)d_in[7];
  const float* bp  = (const float*)d_in[8];
  float* out = (float*)d_out;

  bf16* ws = (bf16*)d_ws;
  const size_t NTOK = 2097152;        // 2*4096*256
  bf16* tn   = ws;
  bf16* fn   = ws + NTOK;
  bf16* q    = ws + 2 * NTOK;
  bf16* k    = ws + 3 * NTOK;
  bf16* vt   = ws + 4 * NTOK;
  bf16* ao   = ws + 5 * NTOK;
  bf16* wqT  = ws + 6 * NTOK;
  bf16* wkvT = wqT + 65536;
  bf16* wpT  = wkvT + 131072;

  transpose_w<<<256, 256, 0, stream>>>(wq, wqT, 256);
  transpose_w<<<512, 256, 0, stream>>>(wkv, wkvT, 512);
  transpose_w<<<256, 256, 0, stream>>>(wp, wpT, 256);
  rms_kernel<<<4096, 256, 0, stream>>>(t, f, nw, tn, fn, 8192);
  gemm_k256<0><<<512, 256, 0, stream>>>(tn, wqT, bq, q, nullptr, nullptr, nullptr, 256);
  gemm_k256<1><<<1024, 256, 0, stream>>>(fn, wkvT, bkv, k, vt, nullptr, nullptr, 512);
  attn_kernel<<<1024, 256, 0, stream>>>(q, k, vt, ao);
  gemm_k256<2><<<512, 256, 0, stream>>>(ao, wpT, bp, nullptr, nullptr, tn, out, 256);
}

// Round 5
// 182.395 us; speedup vs baseline: 2.1175x; 1.0191x over previous
//
#include <hip/hip_runtime.h>

typedef __bf16 bf16;
typedef __bf16 bf16x4 __attribute__((ext_vector_type(4)));
typedef __bf16 bf16x8 __attribute__((ext_vector_type(8)));
typedef float f32x4 __attribute__((ext_vector_type(4)));
typedef float f32x16 __attribute__((ext_vector_type(16)));

__device__ __forceinline__ f32x4 mfma16(bf16x8 a, bf16x8 b, f32x4 c) {
  return __builtin_amdgcn_mfma_f32_16x16x32_bf16(a, b, c, 0, 0, 0);
}
__device__ __forceinline__ f32x16 mfma32(bf16x8 a, bf16x8 b, f32x16 c) {
  return __builtin_amdgcn_mfma_f32_32x32x16_bf16(a, b, c, 0, 0, 0);
}

__device__ __forceinline__ unsigned pack2(float lo, float hi) {
  unsigned short a = __builtin_bit_cast(unsigned short, (bf16)lo);
  unsigned short b = __builtin_bit_cast(unsigned short, (bf16)hi);
  return ((unsigned)b << 16) | (unsigned)a;
}

// ---------------------------------------------------------------------------
// RMSNorm: one wave per 256-elem row. Handles both t and f in one grid.
// ---------------------------------------------------------------------------
__global__ __launch_bounds__(256)
void rms_kernel(const float* __restrict__ t, const float* __restrict__ f,
                const float* __restrict__ w, bf16* __restrict__ tn,
                bf16* __restrict__ fn, int rows_t)
{
  int wave = threadIdx.x >> 6;
  int lane = threadIdx.x & 63;
  int row = blockIdx.x * 4 + wave;
  const float* src;
  bf16* dst;
  if (row < rows_t) {
    src = t + (size_t)row * 256;
    dst = tn + (size_t)row * 256;
  } else {
    int r2 = row - rows_t;
    src = f + (size_t)r2 * 256;
    dst = fn + (size_t)r2 * 256;
  }
  float4 v = reinterpret_cast<const float4*>(src)[lane];
  float ss = v.x * v.x + v.y * v.y + v.z * v.z + v.w * v.w;
  #pragma unroll
  for (int m = 1; m < 64; m <<= 1) ss += __shfl_xor(ss, m);
  float nrm = rsqrtf(ss * (1.0f / 256.0f) + 1e-5f);
  float4 wv = reinterpret_cast<const float4*>(w)[lane];
  bf16x4 o;
  o[0] = (bf16)(v.x * nrm * wv.x);
  o[1] = (bf16)(v.y * nrm * wv.y);
  o[2] = (bf16)(v.z * nrm * wv.z);
  o[3] = (bf16)(v.w * nrm * wv.w);
  *reinterpret_cast<bf16x4*>(dst + lane * 4) = o;
}

// ---------------------------------------------------------------------------
// All three weight transposes fused in one launch.
// dst[n*256 + k] = (bf16) src[k*N + n]
// ---------------------------------------------------------------------------
__global__ __launch_bounds__(256)
void transpose_all(const float* __restrict__ wq, const float* __restrict__ wkv,
                   const float* __restrict__ wp, bf16* __restrict__ wqT,
                   bf16* __restrict__ wkvT, bf16* __restrict__ wpT)
{
  int e = blockIdx.x * 256 + threadIdx.x;   // 0..262143
  const float* src; bf16* dst; int N; int idx;
  if (e < 65536)       { src = wq;  dst = wqT;  N = 256; idx = e; }
  else if (e < 196608) { src = wkv; dst = wkvT; N = 512; idx = e - 65536; }
  else                 { src = wp;  dst = wpT;  N = 256; idx = e - 196608; }
  int k = idx & 255;
  int n = idx >> 8;
  dst[idx] = (bf16)src[(size_t)k * N + n];
}

// ---------------------------------------------------------------------------
// GEMM: out[M=8192, N] = A[8192,256](bf16) @ W[256,N] + bias
// Block tile 64x64, 4 waves in 2x2, each wave 32x32 via 2x2 MFMA frags.
// MODE 0: write Q layout  [b*4+h][t][d]
// MODE 1: write K layout  [b*4+h][f][d]  +  Vt layout [b*4+h][d][f]
// MODE 2: fp32 out = acc + bias + resid(bf16)
// ---------------------------------------------------------------------------
template<int MODE>
__global__ __launch_bounds__(256)
void gemm_k256(const bf16* __restrict__ A, const bf16* __restrict__ Wt,
               const float* __restrict__ bias, bf16* __restrict__ o0,
               bf16* __restrict__ o1, const bf16* __restrict__ resid,
               float* __restrict__ outf, int N)
{
  int wv = threadIdx.x >> 6;
  int lane = threadIdx.x & 63;
  int lr = lane & 15;
  int lk = (lane >> 4) * 8;
  int wm = wv >> 1, wn = wv & 1;
  int nb = N >> 6;
  int bm = blockIdx.x / nb;
  int bn = blockIdx.x - bm * nb;
  int row0 = bm * 64 + wm * 32;
  int col0 = bn * 64 + wn * 32;
  const bf16* Ap = A + (size_t)row0 * 256;
  const bf16* Wp = Wt + (size_t)col0 * 256;

  f32x4 acc[2][2] = {};
  #pragma unroll
  for (int k0 = 0; k0 < 256; k0 += 32) {
    bf16x8 a[2], b[2];
    #pragma unroll
    for (int mi = 0; mi < 2; mi++)
      a[mi] = *reinterpret_cast<const bf16x8*>(Ap + (size_t)(mi * 16 + lr) * 256 + k0 + lk);
    #pragma unroll
    for (int ni = 0; ni < 2; ni++)
      b[ni] = *reinterpret_cast<const bf16x8*>(Wp + (size_t)(ni * 16 + lr) * 256 + k0 + lk);
    #pragma unroll
    for (int mi = 0; mi < 2; mi++)
      #pragma unroll
      for (int ni = 0; ni < 2; ni++)
        acc[mi][ni] = mfma16(a[mi], b[ni], acc[mi][ni]);
  }

  int rb = (lane >> 4) * 4;
  #pragma unroll
  for (int mi = 0; mi < 2; mi++) {
    #pragma unroll
    for (int ni = 0; ni < 2; ni++) {
      int col = col0 + ni * 16 + lr;
      float bv = bias[col];
      #pragma unroll
      for (int r = 0; r < 4; r++) {
        int row = row0 + mi * 16 + rb + r;
        float val = acc[mi][ni][r] + bv;
        if (MODE == 0) {
          int b_ = row >> 12, tt = row & 4095;
          int h = col >> 6, d = col & 63;
          o0[(((size_t)(b_ * 4 + h)) * 4096 + tt) * 64 + d] = (bf16)val;
        } else if (MODE == 1) {
          int b_ = row >> 12, ff = row & 4095;
          if (col < 256) {
            int h = col >> 6, d = col & 63;
            o0[(((size_t)(b_ * 4 + h)) * 4096 + ff) * 64 + d] = (bf16)val;
          } else {
            int c = col - 256;
            int h = c >> 6, d = c & 63;
            o1[(((size_t)(b_ * 4 + h)) * 64 + d) * 4096 + ff] = (bf16)val;
          }
        } else {
          size_t idx = (size_t)row * 256 + col;
          outf[idx] = val + (float)resid[idx];
        }
      }
    }
  }
}

// ---------------------------------------------------------------------------
// Flash attention v3: swapped-operand 32x32 MFMA, in-register softmax,
// register double-buffered K/V prefetch (loads issued one iteration early).
// grid = (B*H=8) * (Nt/32=128) blocks; 4 waves/block, wave wv owns the
// f-range [wv*1024, wv*1024+1024) over the SAME 32 q rows; merge via LDS.
// Q prescaled by (1/8)*log2(e); softmax via exp2f.
// ---------------------------------------------------------------------------
__global__ __launch_bounds__(256)
void attn_kernel(const bf16* __restrict__ Q, const bf16* __restrict__ K,
                 const bf16* __restrict__ Vt, bf16* __restrict__ AO)
{
  int bh = blockIdx.x >> 7;        // 0..7  (b*4+h)
  int tb = blockIdx.x & 127;       // 32-row q tile
  int wv = threadIdx.x >> 6;       // f-split index 0..3
  int lane = threadIdx.x & 63;
  int lq = lane & 31;              // q column (also f-row / d-row for A frags)
  int h32 = lane >> 5;             // lane half
  int t0 = tb * 32;

  const bf16* Qb = Q + ((size_t)bh * 4096 + t0) * 64;
  const bf16* Kb = K + (size_t)bh * 4096 * 64;
  const bf16* Vb = Vt + (size_t)bh * 64 * 4096;

  // Q as B-fragments: B[k][q], k = kc*16 + h32*8 + i. Prescale 1/8 * log2e.
  const float qs = 0.125f * 1.44269504089f;
  bf16x8 qf[4];
  #pragma unroll
  for (int kc = 0; kc < 4; kc++) {
    qf[kc] = *reinterpret_cast<const bf16x8*>(Qb + (size_t)lq * 64 + kc * 16 + h32 * 8);
    #pragma unroll
    for (int i = 0; i < 8; i++) qf[kc][i] = (bf16)((float)qf[kc][i] * qs);
  }

  f32x16 oa[2] = {};               // O^T accumulators (d-blocks 0,1)
  float m = -3.0e38f, l = 0.f;

  int fbeg = wv * 1024;
  int fend = fbeg + 1024;

  // prologue: load first K/V tile into regs
  bf16x8 kcur[4], vcur[4];
  #pragma unroll
  for (int kc = 0; kc < 4; kc++)
    kcur[kc] = *reinterpret_cast<const bf16x8*>(
        Kb + (size_t)(fbeg + lq) * 64 + kc * 16 + h32 * 8);
  #pragma unroll
  for (int db = 0; db < 2; db++) {
    const bf16* vp = Vb + (size_t)(db * 32 + lq) * 4096 + fbeg + h32 * 8;
    vcur[db * 2]     = *reinterpret_cast<const bf16x8*>(vp);
    vcur[db * 2 + 1] = *reinterpret_cast<const bf16x8*>(vp + 16);
  }

  for (int f0 = fbeg; f0 < fend; f0 += 32) {
    // issue NEXT tile's loads first (full iteration of latency hiding)
    int f1 = (f0 + 32 < fend) ? f0 + 32 : fbeg;   // wrap: valid addr, unused
    bf16x8 knxt[4], vnxt[4];
    #pragma unroll
    for (int kc = 0; kc < 4; kc++)
      knxt[kc] = *reinterpret_cast<const bf16x8*>(
          Kb + (size_t)(f1 + lq) * 64 + kc * 16 + h32 * 8);
    #pragma unroll
    for (int db = 0; db < 2; db++) {
      const bf16* vp = Vb + (size_t)(db * 32 + lq) * 4096 + f1 + h32 * 8;
      vnxt[db * 2]     = *reinterpret_cast<const bf16x8*>(vp);
      vnxt[db * 2 + 1] = *reinterpret_cast<const bf16x8*>(vp + 16);
    }

    // S^T (32f x 32q) = K . Q^T   (log2-units)
    f32x16 st = {};
    #pragma unroll
    for (int kc = 0; kc < 4; kc++) st = mfma32(kcur[kc], qf[kc], st);

    // tree max over 16 regs, then cross-half
    float red[8];
    #pragma unroll
    for (int j = 0; j < 8; j++) red[j] = fmaxf(st[2 * j], st[2 * j + 1]);
    #pragma unroll
    for (int sj = 4; sj >= 1; sj >>= 1)
      #pragma unroll
      for (int j = 0; j < sj; j++) red[j] = fmaxf(red[j], red[j + sj]);
    float tm = red[0];
    tm = fmaxf(tm, __shfl_xor(tm, 32));

    // exact skip-rescale: alpha==1 iff no column got a new max
    if (!__all(tm <= m)) {
      float mn = fmaxf(m, tm);
      float alpha = exp2f(m - mn);
      m = mn;
      l *= alpha;
      #pragma unroll
      for (int r = 0; r < 16; r++) { oa[0][r] *= alpha; oa[1][r] *= alpha; }
    }

    // p = exp2(st - m) in place, tree-sum
    #pragma unroll
    for (int r = 0; r < 16; r++) st[r] = exp2f(st[r] - m);
    float sred[8];
    #pragma unroll
    for (int j = 0; j < 8; j++) sred[j] = st[2 * j] + st[2 * j + 1];
    #pragma unroll
    for (int sj = 4; sj >= 1; sj >>= 1)
      #pragma unroll
      for (int j = 0; j < sj; j++) sred[j] += sred[j + sj];
    float ps = sred[0];
    ps += __shfl_xor(ps, 32);
    l += ps;

    // P^T -> B-fragments. w[j] = pack(p[2j], p[2j+1]).
    unsigned w[8];
    #pragma unroll
    for (int j = 0; j < 8; j++) w[j] = pack2(st[2 * j], st[2 * j + 1]);
    // cross-half exchanges: send what the partner needs
    unsigned e0 = (unsigned)__shfl_xor((int)(h32 ? w[0] : w[2]), 32);
    unsigned e1 = (unsigned)__shfl_xor((int)(h32 ? w[1] : w[3]), 32);
    unsigned e2 = (unsigned)__shfl_xor((int)(h32 ? w[4] : w[6]), 32);
    unsigned e3 = (unsigned)__shfl_xor((int)(h32 ? w[5] : w[7]), 32);
    union { unsigned u[4]; bf16x8 v; } ub0, ub1;
    ub0.u[0] = h32 ? e0 : w[0];
    ub0.u[1] = h32 ? e1 : w[1];
    ub0.u[2] = h32 ? w[2] : e0;
    ub0.u[3] = h32 ? w[3] : e1;
    ub1.u[0] = h32 ? e2 : w[4];
    ub1.u[1] = h32 ? e3 : w[5];
    ub1.u[2] = h32 ? w[6] : e2;
    ub1.u[3] = h32 ? w[7] : e3;

    // O^T += Vt . P^T
    #pragma unroll
    for (int db = 0; db < 2; db++) {
      oa[db] = mfma32(vcur[db * 2],     ub0.v, oa[db]);
      oa[db] = mfma32(vcur[db * 2 + 1], ub1.v, oa[db]);
    }

    // rotate prefetch buffers
    #pragma unroll
    for (int i = 0; i < 4; i++) { kcur[i] = knxt[i]; vcur[i] = vnxt[i]; }
  }

  // ---- merge the 4 f-split partials through LDS ----
  __shared__ float ols[4][64][33];
  __shared__ float mls[4][2][32];
  #pragma unroll
  for (int db = 0; db < 2; db++)
    #pragma unroll
    for (int r = 0; r < 16; r++) {
      int d = db * 32 + (r & 3) + 8 * (r >> 2) + 4 * h32;
      ols[wv][d][lq] = oa[db][r];
    }
  if (lane < 32) {
    mls[wv][0][lq] = m;
    mls[wv][1][lq] = l;
  }
  __syncthreads();

  int b_ = bh >> 2, hh = bh & 3;
  #pragma unroll
  for (int j = 0; j < 8; j++) {
    int e = threadIdx.x + j * 256;     // 2048 = 32q x 64d
    int q = e >> 6, d = e & 63;
    float M = fmaxf(fmaxf(mls[0][0][q], mls[1][0][q]),
                    fmaxf(mls[2][0][q], mls[3][0][q]));
    float L = 0.f, O = 0.f;
    #pragma unroll
    for (int s = 0; s < 4; s++) {
      float fs = exp2f(mls[s][0][q] - M);
      L += mls[s][1][q] * fs;
      O += ols[s][d][q] * fs;
    }
    AO[((size_t)b_ * 4096 + t0 + q) * 256 + hh * 64 + d] = (bf16)(O / L);
  }
}

// ---------------------------------------------------------------------------
extern "C" void kernel_launch(void* const* d_in, const int* in_sizes, int n_in,
                              void* d_out, int out_size, void* d_ws, size_t ws_size,
                              hipStream_t stream) {
  const float* t   = (const float*)d_in[0];
  const float* f   = (const float*)d_in[1];
  const float* nw  = (const float*)d_in[2];
  const float* wq  = (const float*)d_in[3];
  const float* bq  = (const float*)d_in[4];
  const float* wkv = (const float*)d_in[5];
  const float* bkv = (const float*)d_in[6];
  const float* wp  = (const float*)d_in[7];
  const float* bp  = (const float*)d_in[8];
  float* out = (float*)d_out;

  bf16* ws = (bf16*)d_ws;
  const size_t NTOK = 2097152;        // 2*4096*256
  bf16* tn   = ws;
  bf16* fn   = ws + NTOK;
  bf16* q    = ws + 2 * NTOK;
  bf16* k    = ws + 3 * NTOK;
  bf16* vt   = ws + 4 * NTOK;
  bf16* ao   = ws + 5 * NTOK;
  bf16* wqT  = ws + 6 * NTOK;
  bf16* wkvT = wqT + 65536;
  bf16* wpT  = wkvT + 131072;

  transpose_all<<<1024, 256, 0, stream>>>(wq, wkv, wp, wqT, wkvT, wpT);
  rms_kernel<<<4096, 256, 0, stream>>>(t, f, nw, tn, fn, 8192);
  gemm_k256<0><<<512, 256, 0, stream>>>(tn, wqT, bq, q, nullptr, nullptr, nullptr, 256);
  gemm_k256<1><<<1024, 256, 0, stream>>>(fn, wkvT, bkv, k, vt, nullptr, nullptr, 512);
  attn_kernel<<<1024, 256, 0, stream>>>(q, k, vt, ao);
  gemm_k256<2><<<512, 256, 0, stream>>>(ao, wpT, bp, nullptr, nullptr, tn, out, 256);
}

// Round 6
// 162.349 us; speedup vs baseline: 2.3790x; 1.1235x over previous
//
#include <hip/hip_runtime.h>

typedef __bf16 bf16;
typedef __bf16 bf16x4 __attribute__((ext_vector_type(4)));
typedef __bf16 bf16x8 __attribute__((ext_vector_type(8)));
typedef float f32x4 __attribute__((ext_vector_type(4)));
typedef float f32x16 __attribute__((ext_vector_type(16)));

__device__ __forceinline__ f32x4 mfma16(bf16x8 a, bf16x8 b, f32x4 c) {
  return __builtin_amdgcn_mfma_f32_16x16x32_bf16(a, b, c, 0, 0, 0);
}
__device__ __forceinline__ f32x16 mfma32(bf16x8 a, bf16x8 b, f32x16 c) {
  return __builtin_amdgcn_mfma_f32_32x32x16_bf16(a, b, c, 0, 0, 0);
}

__device__ __forceinline__ unsigned pack2(float lo, float hi) {
  unsigned short a = __builtin_bit_cast(unsigned short, (bf16)lo);
  unsigned short b = __builtin_bit_cast(unsigned short, (bf16)hi);
  return ((unsigned)b << 16) | (unsigned)a;
}

typedef __attribute__((address_space(3))) unsigned int lds_u32;
typedef __attribute__((address_space(1))) unsigned int glb_u32;
// async global->LDS, 16B per lane; LDS dest = base + lane*16 (wave-linear)
__device__ __forceinline__ void gld16(const bf16* g, bf16* l) {
  __builtin_amdgcn_global_load_lds((const glb_u32*)g, (lds_u32*)l, 16, 0, 0);
}

// ---------------------------------------------------------------------------
// RMSNorm: one wave per 256-elem row. Handles both t and f in one grid.
// ---------------------------------------------------------------------------
__global__ __launch_bounds__(256)
void rms_kernel(const float* __restrict__ t, const float* __restrict__ f,
                const float* __restrict__ w, bf16* __restrict__ tn,
                bf16* __restrict__ fn, int rows_t)
{
  int wave = threadIdx.x >> 6;
  int lane = threadIdx.x & 63;
  int row = blockIdx.x * 4 + wave;
  const float* src;
  bf16* dst;
  if (row < rows_t) {
    src = t + (size_t)row * 256;
    dst = tn + (size_t)row * 256;
  } else {
    int r2 = row - rows_t;
    src = f + (size_t)r2 * 256;
    dst = fn + (size_t)r2 * 256;
  }
  float4 v = reinterpret_cast<const float4*>(src)[lane];
  float ss = v.x * v.x + v.y * v.y + v.z * v.z + v.w * v.w;
  #pragma unroll
  for (int m = 1; m < 64; m <<= 1) ss += __shfl_xor(ss, m);
  float nrm = rsqrtf(ss * (1.0f / 256.0f) + 1e-5f);
  float4 wv = reinterpret_cast<const float4*>(w)[lane];
  bf16x4 o;
  o[0] = (bf16)(v.x * nrm * wv.x);
  o[1] = (bf16)(v.y * nrm * wv.y);
  o[2] = (bf16)(v.z * nrm * wv.z);
  o[3] = (bf16)(v.w * nrm * wv.w);
  *reinterpret_cast<bf16x4*>(dst + lane * 4) = o;
}

// ---------------------------------------------------------------------------
// All three weight transposes fused in one launch.
// dst[n*256 + k] = (bf16) src[k*N + n]
// ---------------------------------------------------------------------------
__global__ __launch_bounds__(256)
void transpose_all(const float* __restrict__ wq, const float* __restrict__ wkv,
                   const float* __restrict__ wp, bf16* __restrict__ wqT,
                   bf16* __restrict__ wkvT, bf16* __restrict__ wpT)
{
  int e = blockIdx.x * 256 + threadIdx.x;   // 0..262143
  const float* src; bf16* dst; int N; int idx;
  if (e < 65536)       { src = wq;  dst = wqT;  N = 256; idx = e; }
  else if (e < 196608) { src = wkv; dst = wkvT; N = 512; idx = e - 65536; }
  else                 { src = wp;  dst = wpT;  N = 256; idx = e - 196608; }
  int k = idx & 255;
  int n = idx >> 8;
  dst[idx] = (bf16)src[(size_t)k * N + n];
}

// ---------------------------------------------------------------------------
// GEMM: out[M=8192, N] = A[8192,256](bf16) @ W[256,N] + bias
// Block tile 64x64, 4 waves in 2x2, each wave 32x32 via 2x2 MFMA frags.
// MODE 0: write Q layout  [b*4+h][t][d]
// MODE 1: write K layout  [b*4+h][f][d]  +  Vt layout [b*4+h][d][f]
// MODE 2: fp32 out = acc + bias + resid(bf16)
// ---------------------------------------------------------------------------
template<int MODE>
__global__ __launch_bounds__(256)
void gemm_k256(const bf16* __restrict__ A, const bf16* __restrict__ Wt,
               const float* __restrict__ bias, bf16* __restrict__ o0,
               bf16* __restrict__ o1, const bf16* __restrict__ resid,
               float* __restrict__ outf, int N)
{
  int wv = threadIdx.x >> 6;
  int lane = threadIdx.x & 63;
  int lr = lane & 15;
  int lk = (lane >> 4) * 8;
  int wm = wv >> 1, wn = wv & 1;
  int nb = N >> 6;
  int bm = blockIdx.x / nb;
  int bn = blockIdx.x - bm * nb;
  int row0 = bm * 64 + wm * 32;
  int col0 = bn * 64 + wn * 32;
  const bf16* Ap = A + (size_t)row0 * 256;
  const bf16* Wp = Wt + (size_t)col0 * 256;

  f32x4 acc[2][2] = {};
  #pragma unroll
  for (int k0 = 0; k0 < 256; k0 += 32) {
    bf16x8 a[2], b[2];
    #pragma unroll
    for (int mi = 0; mi < 2; mi++)
      a[mi] = *reinterpret_cast<const bf16x8*>(Ap + (size_t)(mi * 16 + lr) * 256 + k0 + lk);
    #pragma unroll
    for (int ni = 0; ni < 2; ni++)
      b[ni] = *reinterpret_cast<const bf16x8*>(Wp + (size_t)(ni * 16 + lr) * 256 + k0 + lk);
    #pragma unroll
    for (int mi = 0; mi < 2; mi++)
      #pragma unroll
      for (int ni = 0; ni < 2; ni++)
        acc[mi][ni] = mfma16(a[mi], b[ni], acc[mi][ni]);
  }

  int rb = (lane >> 4) * 4;
  #pragma unroll
  for (int mi = 0; mi < 2; mi++) {
    #pragma unroll
    for (int ni = 0; ni < 2; ni++) {
      int col = col0 + ni * 16 + lr;
      float bv = bias[col];
      #pragma unroll
      for (int r = 0; r < 4; r++) {
        int row = row0 + mi * 16 + rb + r;
        float val = acc[mi][ni][r] + bv;
        if (MODE == 0) {
          int b_ = row >> 12, tt = row & 4095;
          int h = col >> 6, d = col & 63;
          o0[(((size_t)(b_ * 4 + h)) * 4096 + tt) * 64 + d] = (bf16)val;
        } else if (MODE == 1) {
          int b_ = row >> 12, ff = row & 4095;
          if (col < 256) {
            int h = col >> 6, d = col & 63;
            o0[(((size_t)(b_ * 4 + h)) * 4096 + ff) * 64 + d] = (bf16)val;
          } else {
            int c = col - 256;
            int h = c >> 6, d = c & 63;
            o1[(((size_t)(b_ * 4 + h)) * 64 + d) * 4096 + ff] = (bf16)val;
          }
        } else {
          size_t idx = (size_t)row * 256 + col;
          outf[idx] = val + (float)resid[idx];
        }
      }
    }
  }
}

// ---------------------------------------------------------------------------
// Flash attention v4: LDS-shared K/V, cache-traffic-optimized.
// grid = 512 blocks: bh = blockIdx&7 (XCD-partition: each XCD caches ONE
// head's 1MB K/V in its private L2), qb = blockIdx>>3 (64 q rows).
// Block: 4 waves = 2 q-tiles (qi) x 2 f-halves (fh). The two waves of an
// f-stream share K/V tiles staged in LDS via global_load_lds (16B), double
// buffered, one vmcnt(0)+barrier per 32-f tile.
// LDS layouts (per stream, per buf): K' [8 dch][32 f][16B], V' [4 fch][64 d][16B]
// -> both staging writes and ds_read_b128 fragment reads are full-wave
// contiguous (conflict-free).
// Swapped-operand 32x32 MFMA, in-register softmax (log2 units), deferred
// cross-half l-sum (merged in epilogue).
// ---------------------------------------------------------------------------
__global__ __launch_bounds__(256)
void attn_kernel(const bf16* __restrict__ Q, const bf16* __restrict__ K,
                 const bf16* __restrict__ Vt, bf16* __restrict__ AO)
{
  int bh = blockIdx.x & 7;         // head index == XCD index (round-robin)
  int qb = blockIdx.x >> 3;        // 0..63, 64-row q block
  int wv = threadIdx.x >> 6;
  int fh = wv >> 1;                // f-half 0..1
  int qi = wv & 1;                 // q-tile 0..1
  int lane = threadIdx.x & 63;
  int lq = lane & 31;
  int h32 = lane >> 5;

  const bf16* Qb = Q + ((size_t)bh * 4096 + qb * 64 + qi * 32) * 64;
  const bf16* Kb = K + (size_t)bh * 4096 * 64;
  const bf16* Vb = Vt + (size_t)bh * 64 * 4096;

  __shared__ union {
    bf16 stage[2][2][4096];        // [fh][buf][ K' 2048 | V' 2048 ] bf16
    struct {
      float o[4][64][33];          // per-wave unnormalized O^T
      float mm[4][32];             // per-wave m per q
      float lh[4][2][32];          // per-wave per-half l per q
    } mg;
  } lds;

  // Q as B-fragments: B[k][q], k = kc*16 + h32*8 + i. Prescale 1/8*log2e.
  const float qs = 0.125f * 1.44269504089f;
  bf16x8 qf[4];
  #pragma unroll
  for (int kc = 0; kc < 4; kc++) {
    qf[kc] = *reinterpret_cast<const bf16x8*>(Qb + (size_t)lq * 64 + kc * 16 + h32 * 8);
    #pragma unroll
    for (int i = 0; i < 8; i++) qf[kc][i] = (bf16)((float)qf[kc][i] * qs);
  }

  f32x16 oa[2] = {};
  float m = -3.0e38f, l = 0.f;

  int fbeg = fh * 2048;

  // stage one 32-f tile (K by qi==0 wave, V by qi==1 wave of this stream)
  auto STAGE = [&](int buf, int ft) {
    bf16* sb = &lds.stage[fh][buf][0];
    if (qi == 0) {
      #pragma unroll
      for (int j = 0; j < 4; j++) {
        const bf16* src = Kb + (size_t)(ft + lq) * 64 + (j * 2 + h32) * 8;
        gld16(src, sb + j * 512);              // K': dch-major
      }
    } else {
      #pragma unroll
      for (int j = 0; j < 4; j++) {
        const bf16* src = Vb + (size_t)lane * 4096 + ft + j * 8;
        gld16(src, sb + 2048 + j * 512);       // V': fch-major
      }
    }
  };

  STAGE(0, fbeg);
  asm volatile("s_waitcnt vmcnt(0)");
  __syncthreads();

  int c = 0;
  for (int t = 0; t < 64; ++t) {
    if (t < 63) STAGE(c ^ 1, fbeg + (t + 1) * 32);

    const bf16* kb = &lds.stage[fh][c][0];
    const bf16* vb = kb + 2048;

    // S^T (32f x 32q) = K . Q^T   (log2 units)
    f32x16 st = {};
    #pragma unroll
    for (int kc = 0; kc < 4; kc++) {
      bf16x8 kf = *reinterpret_cast<const bf16x8*>(kb + (kc * 2 + h32) * 256 + lq * 8);
      st = mfma32(kf, qf[kc], st);
    }

    // tree max over 16 regs, then cross-half
    float red[8];
    #pragma unroll
    for (int j = 0; j < 8; j++) red[j] = fmaxf(st[2 * j], st[2 * j + 1]);
    #pragma unroll
    for (int sj = 4; sj >= 1; sj >>= 1)
      #pragma unroll
      for (int j = 0; j < sj; j++) red[j] = fmaxf(red[j], red[j + sj]);
    float tm = red[0];
    tm = fmaxf(tm, __shfl_xor(tm, 32));

    // exact skip-rescale: alpha==1 iff no column got a new max
    if (!__all(tm <= m)) {
      float mn = fmaxf(m, tm);
      float alpha = exp2f(m - mn);
      m = mn;
      l *= alpha;
      #pragma unroll
      for (int r = 0; r < 16; r++) { oa[0][r] *= alpha; oa[1][r] *= alpha; }
    }

    // p = exp2(st - m) in place; per-half sum only (halves merged at end)
    #pragma unroll
    for (int r = 0; r < 16; r++) st[r] = exp2f(st[r] - m);
    float sred[8];
    #pragma unroll
    for (int j = 0; j < 8; j++) sred[j] = st[2 * j] + st[2 * j + 1];
    #pragma unroll
    for (int sj = 4; sj >= 1; sj >>= 1)
      #pragma unroll
      for (int j = 0; j < sj; j++) sred[j] += sred[j + sj];
    l += sred[0];

    // P^T -> B-fragments. w[j] = pack(p[2j], p[2j+1]).
    unsigned w[8];
    #pragma unroll
    for (int j = 0; j < 8; j++) w[j] = pack2(st[2 * j], st[2 * j + 1]);
    unsigned e0 = (unsigned)__shfl_xor((int)(h32 ? w[0] : w[2]), 32);
    unsigned e1 = (unsigned)__shfl_xor((int)(h32 ? w[1] : w[3]), 32);
    unsigned e2 = (unsigned)__shfl_xor((int)(h32 ? w[4] : w[6]), 32);
    unsigned e3 = (unsigned)__shfl_xor((int)(h32 ? w[5] : w[7]), 32);
    union { unsigned u[4]; bf16x8 v; } ub0, ub1;
    ub0.u[0] = h32 ? e0 : w[0];
    ub0.u[1] = h32 ? e1 : w[1];
    ub0.u[2] = h32 ? w[2] : e0;
    ub0.u[3] = h32 ? w[3] : e1;
    ub1.u[0] = h32 ? e2 : w[4];
    ub1.u[1] = h32 ? e3 : w[5];
    ub1.u[2] = h32 ? w[6] : e2;
    ub1.u[3] = h32 ? w[7] : e3;

    // O^T += Vt . P^T  (V fragments from LDS)
    #pragma unroll
    for (int db = 0; db < 2; db++) {
      bf16x8 v0 = *reinterpret_cast<const bf16x8*>(vb + (0 + h32) * 512 + (db * 32 + lq) * 8);
      bf16x8 v1 = *reinterpret_cast<const bf16x8*>(vb + (2 + h32) * 512 + (db * 32 + lq) * 8);
      oa[db] = mfma32(v0, ub0.v, oa[db]);
      oa[db] = mfma32(v1, ub1.v, oa[db]);
    }

    asm volatile("s_waitcnt vmcnt(0)");
    __syncthreads();
    c ^= 1;
  }

  // ---- merge the 2 f-half partials per q-tile through LDS ----
  #pragma unroll
  for (int db = 0; db < 2; db++)
    #pragma unroll
    for (int r = 0; r < 16; r++) {
      int d = db * 32 + (r & 3) + 8 * (r >> 2) + 4 * h32;
      lds.mg.o[wv][d][lq] = oa[db][r];
    }
  if (lane < 32) lds.mg.mm[wv][lq] = m;
  lds.mg.lh[wv][h32][lq] = l;
  __syncthreads();

  int b_ = bh >> 2, hh = bh & 3;
  int tid = threadIdx.x;
  #pragma unroll
  for (int j = 0; j < 16; j++) {
    int e = tid + j * 256;            // 4096 = 2 tiles x 32 q x 64 d
    int ti = e >> 11;
    int q = (e >> 6) & 31;
    int d = e & 63;
    int wA = ti, wB = ti + 2;         // fh=0 and fh=1 partials of q-tile ti
    float mA = lds.mg.mm[wA][q], mB = lds.mg.mm[wB][q];
    float M = fmaxf(mA, mB);
    float eA = exp2f(mA - M), eB = exp2f(mB - M);
    float L = (lds.mg.lh[wA][0][q] + lds.mg.lh[wA][1][q]) * eA
            + (lds.mg.lh[wB][0][q] + lds.mg.lh[wB][1][q]) * eB;
    float O = lds.mg.o[wA][d][q] * eA + lds.mg.o[wB][d][q] * eB;
    int row = qb * 64 + ti * 32 + q;
    AO[((size_t)b_ * 4096 + row) * 256 + hh * 64 + d] = (bf16)(O / L);
  }
}

// ---------------------------------------------------------------------------
extern "C" void kernel_launch(void* const* d_in, const int* in_sizes, int n_in,
                              void* d_out, int out_size, void* d_ws, size_t ws_size,
                              hipStream_t stream) {
  const float* t   = (const float*)d_in[0];
  const float* f   = (const float*)d_in[1];
  const float* nw  = (const float*)d_in[2];
  const float* wq  = (const float*)d_in[3];
  const float* bq  = (const float*)d_in[4];
  const float* wkv = (const float*)d_in[5];
  const float* bkv = (const float*)d_in[6];
  const float* wp  = (const float*)d_in[7];
  const float* bp  = (const float*)d_in[8];
  float* out = (float*)d_out;

  bf16* ws = (bf16*)d_ws;
  const size_t NTOK = 2097152;        // 2*4096*256
  bf16* tn   = ws;
  bf16* fn   = ws + NTOK;
  bf16* q    = ws + 2 * NTOK;
  bf16* k    = ws + 3 * NTOK;
  bf16* vt   = ws + 4 * NTOK;
  bf16* ao   = ws + 5 * NTOK;
  bf16* wqT  = ws + 6 * NTOK;
  bf16* wkvT = wqT + 65536;
  bf16* wpT  = wkvT + 131072;

  transpose_all<<<1024, 256, 0, stream>>>(wq, wkv, wp, wqT, wkvT, wpT);
  rms_kernel<<<4096, 256, 0, stream>>>(t, f, nw, tn, fn, 8192);
  gemm_k256<0><<<512, 256, 0, stream>>>(tn, wqT, bq, q, nullptr, nullptr, nullptr, 256);
  gemm_k256<1><<<1024, 256, 0, stream>>>(fn, wkvT, bkv, k, vt, nullptr, nullptr, 512);
  attn_kernel<<<512, 256, 0, stream>>>(q, k, vt, ao);
  gemm_k256<2><<<512, 256, 0, stream>>>(ao, wpT, bp, nullptr, nullptr, tn, out, 256);
}

// Round 7
// 141.718 us; speedup vs baseline: 2.7253x; 1.1456x over previous
//
#include <hip/hip_runtime.h>

typedef __bf16 bf16;
typedef __bf16 bf16x4 __attribute__((ext_vector_type(4)));
typedef __bf16 bf16x8 __attribute__((ext_vector_type(8)));
typedef float f32x4 __attribute__((ext_vector_type(4)));
typedef float f32x16 __attribute__((ext_vector_type(16)));

__device__ __forceinline__ f32x4 mfma16(bf16x8 a, bf16x8 b, f32x4 c) {
  return __builtin_amdgcn_mfma_f32_16x16x32_bf16(a, b, c, 0, 0, 0);
}
__device__ __forceinline__ f32x16 mfma32(bf16x8 a, bf16x8 b, f32x16 c) {
  return __builtin_amdgcn_mfma_f32_32x32x16_bf16(a, b, c, 0, 0, 0);
}

__device__ __forceinline__ unsigned pack2(float lo, float hi) {
  unsigned short a = __builtin_bit_cast(unsigned short, (bf16)lo);
  unsigned short b = __builtin_bit_cast(unsigned short, (bf16)hi);
  return ((unsigned)b << 16) | (unsigned)a;
}

// v_permlane32_swap_b32 a, b:  a' = {a.lo, b.lo}, b' = {a.hi, b.hi}
__device__ __forceinline__ void plane32swap(unsigned& a, unsigned& b) {
  asm volatile("v_permlane32_swap_b32 %0, %1" : "+v"(a), "+v"(b));
}

typedef __attribute__((address_space(3))) unsigned int lds_u32;
typedef __attribute__((address_space(1))) unsigned int glb_u32;
// async global->LDS, 16B per lane; LDS dest = base + lane*16 (wave-linear)
__device__ __forceinline__ void gld16(const bf16* g, bf16* l) {
  __builtin_amdgcn_global_load_lds((const glb_u32*)g, (lds_u32*)l, 16, 0, 0);
}

// ---------------------------------------------------------------------------
// RMSNorm: one wave per 256-elem row. Handles both t and f in one grid.
// ---------------------------------------------------------------------------
__global__ __launch_bounds__(256)
void rms_kernel(const float* __restrict__ t, const float* __restrict__ f,
                const float* __restrict__ w, bf16* __restrict__ tn,
                bf16* __restrict__ fn, int rows_t)
{
  int wave = threadIdx.x >> 6;
  int lane = threadIdx.x & 63;
  int row = blockIdx.x * 4 + wave;
  const float* src;
  bf16* dst;
  if (row < rows_t) {
    src = t + (size_t)row * 256;
    dst = tn + (size_t)row * 256;
  } else {
    int r2 = row - rows_t;
    src = f + (size_t)r2 * 256;
    dst = fn + (size_t)r2 * 256;
  }
  float4 v = reinterpret_cast<const float4*>(src)[lane];
  float ss = v.x * v.x + v.y * v.y + v.z * v.z + v.w * v.w;
  #pragma unroll
  for (int m = 1; m < 64; m <<= 1) ss += __shfl_xor(ss, m);
  float nrm = rsqrtf(ss * (1.0f / 256.0f) + 1e-5f);
  float4 wv = reinterpret_cast<const float4*>(w)[lane];
  bf16x4 o;
  o[0] = (bf16)(v.x * nrm * wv.x);
  o[1] = (bf16)(v.y * nrm * wv.y);
  o[2] = (bf16)(v.z * nrm * wv.z);
  o[3] = (bf16)(v.w * nrm * wv.w);
  *reinterpret_cast<bf16x4*>(dst + lane * 4) = o;
}

// ---------------------------------------------------------------------------
// All three weight transposes fused in one launch.
// ---------------------------------------------------------------------------
__global__ __launch_bounds__(256)
void transpose_all(const float* __restrict__ wq, const float* __restrict__ wkv,
                   const float* __restrict__ wp, bf16* __restrict__ wqT,
                   bf16* __restrict__ wkvT, bf16* __restrict__ wpT)
{
  int e = blockIdx.x * 256 + threadIdx.x;   // 0..262143
  const float* src; bf16* dst; int N; int idx;
  if (e < 65536)       { src = wq;  dst = wqT;  N = 256; idx = e; }
  else if (e < 196608) { src = wkv; dst = wkvT; N = 512; idx = e - 65536; }
  else                 { src = wp;  dst = wpT;  N = 256; idx = e - 196608; }
  int k = idx & 255;
  int n = idx >> 8;
  dst[idx] = (bf16)src[(size_t)k * N + n];
}

// ---------------------------------------------------------------------------
// GEMM: out[M=8192, N] = A[8192,256](bf16) @ W[256,N] + bias
// ---------------------------------------------------------------------------
template<int MODE>
__global__ __launch_bounds__(256)
void gemm_k256(const bf16* __restrict__ A, const bf16* __restrict__ Wt,
               const float* __restrict__ bias, bf16* __restrict__ o0,
               bf16* __restrict__ o1, const bf16* __restrict__ resid,
               float* __restrict__ outf, int N)
{
  int wv = threadIdx.x >> 6;
  int lane = threadIdx.x & 63;
  int lr = lane & 15;
  int lk = (lane >> 4) * 8;
  int wm = wv >> 1, wn = wv & 1;
  int nb = N >> 6;
  int bm = blockIdx.x / nb;
  int bn = blockIdx.x - bm * nb;
  int row0 = bm * 64 + wm * 32;
  int col0 = bn * 64 + wn * 32;
  const bf16* Ap = A + (size_t)row0 * 256;
  const bf16* Wp = Wt + (size_t)col0 * 256;

  f32x4 acc[2][2] = {};
  #pragma unroll
  for (int k0 = 0; k0 < 256; k0 += 32) {
    bf16x8 a[2], b[2];
    #pragma unroll
    for (int mi = 0; mi < 2; mi++)
      a[mi] = *reinterpret_cast<const bf16x8*>(Ap + (size_t)(mi * 16 + lr) * 256 + k0 + lk);
    #pragma unroll
    for (int ni = 0; ni < 2; ni++)
      b[ni] = *reinterpret_cast<const bf16x8*>(Wp + (size_t)(ni * 16 + lr) * 256 + k0 + lk);
    #pragma unroll
    for (int mi = 0; mi < 2; mi++)
      #pragma unroll
      for (int ni = 0; ni < 2; ni++)
        acc[mi][ni] = mfma16(a[mi], b[ni], acc[mi][ni]);
  }

  int rb = (lane >> 4) * 4;
  #pragma unroll
  for (int mi = 0; mi < 2; mi++) {
    #pragma unroll
    for (int ni = 0; ni < 2; ni++) {
      int col = col0 + ni * 16 + lr;
      float bv = bias[col];
      #pragma unroll
      for (int r = 0; r < 4; r++) {
        int row = row0 + mi * 16 + rb + r;
        float val = acc[mi][ni][r] + bv;
        if (MODE == 0) {
          int b_ = row >> 12, tt = row & 4095;
          int h = col >> 6, d = col & 63;
          o0[(((size_t)(b_ * 4 + h)) * 4096 + tt) * 64 + d] = (bf16)val;
        } else if (MODE == 1) {
          int b_ = row >> 12, ff = row & 4095;
          if (col < 256) {
            int h = col >> 6, d = col & 63;
            o0[(((size_t)(b_ * 4 + h)) * 4096 + ff) * 64 + d] = (bf16)val;
          } else {
            int c = col - 256;
            int h = c >> 6, d = c & 63;
            o1[(((size_t)(b_ * 4 + h)) * 64 + d) * 4096 + ff] = (bf16)val;
          }
        } else {
          size_t idx = (size_t)row * 256 + col;
          outf[idx] = val + (float)resid[idx];
        }
      }
    }
  }
}

// ---------------------------------------------------------------------------
// Flash attention v5: LDS-shared K/V + cross-block f-split for occupancy.
// grid = 1024 blocks: bh = blockIdx&7 (XCD affinity), qb = (blockIdx>>3)&63
// (64 q rows), FQ = blockIdx>>9 (f-half 0/1, 2048 f each).
// Block: 4 waves = 2 q-tiles (qi) x 2 f-streams (fh, 1024 f each).
// Per 32-f tile: K/V staged in LDS (global_load_lds 16B), double-buffered.
// Swapped 32x32 MFMA; in-register softmax (log2 units); defer-max THR=8;
// permlane32_swap for all cross-half exchanges. In-block fh-merge, then
// unnormalized partials (O bf16, m/l f32) to ws; merge_kernel combines FQ.
// ---------------------------------------------------------------------------
__global__ __launch_bounds__(256, 4)
void attn_kernel(const bf16* __restrict__ Q, const bf16* __restrict__ K,
                 const bf16* __restrict__ Vt, bf16* __restrict__ Opart,
                 float2* __restrict__ MLp)
{
  int bh = blockIdx.x & 7;
  int qb = (blockIdx.x >> 3) & 63;
  int FQ = blockIdx.x >> 9;
  int wv = threadIdx.x >> 6;
  int fh = wv >> 1;                // f-stream 0..1
  int qi = wv & 1;                 // q-tile 0..1
  int lane = threadIdx.x & 63;
  int lq = lane & 31;
  int h32 = lane >> 5;

  const bf16* Qb = Q + ((size_t)bh * 4096 + qb * 64 + qi * 32) * 64;
  const bf16* Kb = K + (size_t)bh * 4096 * 64;
  const bf16* Vb = Vt + (size_t)bh * 64 * 4096;

  __shared__ union {
    bf16 stage[2][2][4096];        // [fh][buf][ K' 2048 | V' 2048 ]
    struct {
      float o[4][64][33];
      float mm[4][32];
      float lh[4][2][32];
    } mg;
  } lds;

  const float qs = 0.125f * 1.44269504089f;
  bf16x8 qf[4];
  #pragma unroll
  for (int kc = 0; kc < 4; kc++) {
    qf[kc] = *reinterpret_cast<const bf16x8*>(Qb + (size_t)lq * 64 + kc * 16 + h32 * 8);
    #pragma unroll
    for (int i = 0; i < 8; i++) qf[kc][i] = (bf16)((float)qf[kc][i] * qs);
  }

  f32x16 oa[2] = {};
  float m = -3.0e38f, l = 0.f;

  int fbeg = FQ * 2048 + fh * 1024;

  auto STAGE = [&](int buf, int ft) {
    bf16* sb = &lds.stage[fh][buf][0];
    if (qi == 0) {
      #pragma unroll
      for (int j = 0; j < 4; j++) {
        const bf16* src = Kb + (size_t)(ft + lq) * 64 + (j * 2 + h32) * 8;
        gld16(src, sb + j * 512);              // K': dch-major
      }
    } else {
      #pragma unroll
      for (int j = 0; j < 4; j++) {
        const bf16* src = Vb + (size_t)lane * 4096 + ft + j * 8;
        gld16(src, sb + 2048 + j * 512);       // V': fch-major
      }
    }
  };

  STAGE(0, fbeg);
  asm volatile("s_waitcnt vmcnt(0)");
  __syncthreads();

  int c = 0;
  for (int t = 0; t < 32; ++t) {
    if (t < 31) STAGE(c ^ 1, fbeg + (t + 1) * 32);

    const bf16* kb = &lds.stage[fh][c][0];
    const bf16* vb = kb + 2048;

    // S^T (32f x 32q) = K . Q^T   (log2 units)
    f32x16 st = {};
    #pragma unroll
    for (int kc = 0; kc < 4; kc++) {
      bf16x8 kf = *reinterpret_cast<const bf16x8*>(kb + (kc * 2 + h32) * 256 + lq * 8);
      st = mfma32(kf, qf[kc], st);
    }

    // tree max over 16 regs, then cross-half via permlane32_swap
    float red[8];
    #pragma unroll
    for (int j = 0; j < 8; j++) red[j] = fmaxf(st[2 * j], st[2 * j + 1]);
    #pragma unroll
    for (int sj = 4; sj >= 1; sj >>= 1)
      #pragma unroll
      for (int j = 0; j < sj; j++) red[j] = fmaxf(red[j], red[j + sj]);
    float tm = red[0];
    {
      unsigned x = __builtin_bit_cast(unsigned, tm);
      unsigned y = x;
      plane32swap(x, y);   // x={lo,lo}, y={hi,hi}
      tm = fmaxf(__builtin_bit_cast(float, x), __builtin_bit_cast(float, y));
    }

    // defer-max: rescale only if some column grew its max by > 8 (log2)
    if (!__all(tm - m <= 8.0f)) {
      float mn = fmaxf(m, tm);
      float alpha = exp2f(m - mn);
      m = mn;
      l *= alpha;
      #pragma unroll
      for (int r = 0; r < 16; r++) { oa[0][r] *= alpha; oa[1][r] *= alpha; }
    }

    // p = exp2(st - m); per-half sum (halves merged at epilogue)
    #pragma unroll
    for (int r = 0; r < 16; r++) st[r] = exp2f(st[r] - m);
    float sred[8];
    #pragma unroll
    for (int j = 0; j < 8; j++) sred[j] = st[2 * j] + st[2 * j + 1];
    #pragma unroll
    for (int sj = 4; sj >= 1; sj >>= 1)
      #pragma unroll
      for (int j = 0; j < sj; j++) sred[j] += sred[j + sj];
    l += sred[0];

    // P^T -> B-fragments: pack then permlane32_swap pairs (w0,w2),(w1,w3),...
    unsigned w[8];
    #pragma unroll
    for (int j = 0; j < 8; j++) w[j] = pack2(st[2 * j], st[2 * j + 1]);
    plane32swap(w[0], w[2]);
    plane32swap(w[1], w[3]);
    plane32swap(w[4], w[6]);
    plane32swap(w[5], w[7]);
    union { unsigned u[4]; bf16x8 v; } ub0, ub1;
    ub0.u[0] = w[0]; ub0.u[1] = w[1]; ub0.u[2] = w[2]; ub0.u[3] = w[3];
    ub1.u[0] = w[4]; ub1.u[1] = w[5]; ub1.u[2] = w[6]; ub1.u[3] = w[7];

    // O^T += Vt . P^T  (V fragments from LDS)
    #pragma unroll
    for (int db = 0; db < 2; db++) {
      bf16x8 v0 = *reinterpret_cast<const bf16x8*>(vb + (0 + h32) * 512 + (db * 32 + lq) * 8);
      bf16x8 v1 = *reinterpret_cast<const bf16x8*>(vb + (2 + h32) * 512 + (db * 32 + lq) * 8);
      oa[db] = mfma32(v0, ub0.v, oa[db]);
      oa[db] = mfma32(v1, ub1.v, oa[db]);
    }

    asm volatile("s_waitcnt vmcnt(0)");
    __syncthreads();
    c ^= 1;
  }

  // ---- in-block merge of the 2 f-stream partials per q-tile ----
  #pragma unroll
  for (int db = 0; db < 2; db++)
    #pragma unroll
    for (int r = 0; r < 16; r++) {
      int d = db * 32 + (r & 3) + 8 * (r >> 2) + 4 * h32;
      lds.mg.o[wv][d][lq] = oa[db][r];
    }
  if (lane < 32) lds.mg.mm[wv][lq] = m;
  lds.mg.lh[wv][h32][lq] = l;
  __syncthreads();

  int tid = threadIdx.x;
  #pragma unroll
  for (int j = 0; j < 16; j++) {
    int e = tid + j * 256;            // 4096 = 2 tiles x 32 q x 64 d
    int ti = e >> 11;
    int q = (e >> 6) & 31;
    int d = e & 63;
    int wA = ti, wB = ti + 2;
    float mA = lds.mg.mm[wA][q], mB = lds.mg.mm[wB][q];
    float M = fmaxf(mA, mB);
    float eA = exp2f(mA - M), eB = exp2f(mB - M);
    float L = (lds.mg.lh[wA][0][q] + lds.mg.lh[wA][1][q]) * eA
            + (lds.mg.lh[wB][0][q] + lds.mg.lh[wB][1][q]) * eB;
    float O = lds.mg.o[wA][d][q] * eA + lds.mg.o[wB][d][q] * eB;
    int row = qb * 64 + ti * 32 + q;
    size_t ridx = ((size_t)FQ * 8 + bh) * 4096 + row;
    Opart[ridx * 64 + d] = (bf16)O;           // unnormalized partial
    if (d == 0) MLp[ridx] = make_float2(M, L);
  }
}

// ---------------------------------------------------------------------------
// Combine the 2 cross-block f-half partials -> AO[b][t][h*64+d] (bf16).
// 8 lanes per row (16B each), fully coalesced.
// ---------------------------------------------------------------------------
__global__ __launch_bounds__(256)
void merge_kernel(const bf16* __restrict__ Op, const float2* __restrict__ MLp,
                  bf16* __restrict__ AO)
{
  int e = blockIdx.x * 256 + threadIdx.x;   // 0..262143
  int rid = e >> 3, dc = e & 7;
  int bh = rid >> 12, row = rid & 4095;
  float2 ml0 = MLp[(size_t)bh * 4096 + row];
  float2 ml1 = MLp[(size_t)(8 + bh) * 4096 + row];
  float M = fmaxf(ml0.x, ml1.x);
  float s0 = exp2f(ml0.x - M), s1 = exp2f(ml1.x - M);
  float inv = 1.f / (ml0.y * s0 + ml1.y * s1);
  s0 *= inv; s1 *= inv;
  bf16x8 a = *reinterpret_cast<const bf16x8*>(Op + ((size_t)bh * 4096 + row) * 64 + dc * 8);
  bf16x8 b = *reinterpret_cast<const bf16x8*>(Op + ((size_t)(8 + bh) * 4096 + row) * 64 + dc * 8);
  bf16x8 o;
  #pragma unroll
  for (int i = 0; i < 8; i++)
    o[i] = (bf16)((float)a[i] * s0 + (float)b[i] * s1);
  int b_ = bh >> 2, hh = bh & 3;
  *reinterpret_cast<bf16x8*>(AO + ((size_t)b_ * 4096 + row) * 256 + hh * 64 + dc * 8) = o;
}

// ---------------------------------------------------------------------------
extern "C" void kernel_launch(void* const* d_in, const int* in_sizes, int n_in,
                              void* d_out, int out_size, void* d_ws, size_t ws_size,
                              hipStream_t stream) {
  const float* t   = (const float*)d_in[0];
  const float* f   = (const float*)d_in[1];
  const float* nw  = (const float*)d_in[2];
  const float* wq  = (const float*)d_in[3];
  const float* bq  = (const float*)d_in[4];
  const float* wkv = (const float*)d_in[5];
  const float* bkv = (const float*)d_in[6];
  const float* wp  = (const float*)d_in[7];
  const float* bp  = (const float*)d_in[8];
  float* out = (float*)d_out;

  bf16* ws = (bf16*)d_ws;
  const size_t NTOK = 2097152;        // 2*4096*256
  bf16* tn   = ws;
  bf16* fn   = ws + NTOK;
  bf16* q    = ws + 2 * NTOK;
  bf16* k    = ws + 3 * NTOK;
  bf16* vt   = ws + 4 * NTOK;
  bf16* ao   = ws + 5 * NTOK;
  bf16* wqT  = ws + 6 * NTOK;
  bf16* wkvT = wqT + 65536;
  bf16* wpT  = wkvT + 131072;
  bf16* opart = wpT + 65536;                        // 2*8*4096*64 bf16 = 8 MB
  float2* mlp = (float2*)(opart + (size_t)2 * 8 * 4096 * 64);  // 512 KB

  transpose_all<<<1024, 256, 0, stream>>>(wq, wkv, wp, wqT, wkvT, wpT);
  rms_kernel<<<4096, 256, 0, stream>>>(t, f, nw, tn, fn, 8192);
  gemm_k256<0><<<512, 256, 0, stream>>>(tn, wqT, bq, q, nullptr, nullptr, nullptr, 256);
  gemm_k256<1><<<1024, 256, 0, stream>>>(fn, wkvT, bkv, k, vt, nullptr, nullptr, 512);
  attn_kernel<<<1024, 256, 0, stream>>>(q, k, vt, opart, mlp);
  merge_kernel<<<1024, 256, 0, stream>>>(opart, mlp, ao);
  gemm_k256<2><<<512, 256, 0, stream>>>(ao, wpT, bp, nullptr, nullptr, tn, out, 256);
}